// Round 4
// baseline (432.814 us; speedup 1.0000x reference)
//
#include <hip/hip_runtime.h>
#include <math.h>

// ---------------------------------------------------------------------------
// N=100000, E=1600000, dims 128. Round 10:
//  - r9 (425 us) + XCD-local counting atomics, replica-MAJOR layout:
//    cnt8[xcd*N + node] (64-bit: count<<32 | wq) updated at WORKGROUP scope
//    -> RMW executes in the local XCD's L2 (no per-op HBM write-through).
//    Each XCD owns a private contiguous 800 KB slice (L2-resident, no line
//    sharing; r8's node-major layout shared every line across all 8 XCDs).
//    Correct because replicas are partitioned by the ACTUAL XCD
//    (s_getreg HW_REG_XCC_ID, m09-verified); per-XCD-L2 atomicity covers
//    exactly the updaters of each replica.
//  - Weighted degree accumulated by the same atomic -> k_degsum eliminated,
//    k_scatter no longer reads ew. aux[e] = rank:14 | xcd:3 | wq:15
//    (requires per-(node,XCD) rank < 2^14; avg degree here is 16).
//  - Overlays keep footprint at r9's proven 90.8 MB: bas on mnb head (dead
//    before k_pull writes mnb), recs on cnt8 (dead after k_base).
//  - Fallback path for N > 2^17 = exact r9 pipeline (device atomics).
// ---------------------------------------------------------------------------

typedef __attribute__((ext_vector_type(8))) short short8;   // 8 bf16 (4 VGPR)
typedef __attribute__((ext_vector_type(4))) float float4v;  // 4 fp32 acc

#define WQ_SCALE 32767.0f
#define WQ_INV   (1.0f / 32767.0f)

__device__ __forceinline__ unsigned f2bf_pack(float a, float b) {
    unsigned ua = __float_as_uint(a);
    unsigned ub = __float_as_uint(b);
    ua += 0x7FFF + ((ua >> 16) & 1);   // RNE
    ub += 0x7FFF + ((ub >> 16) & 1);
    return (ua >> 16) | (ub & 0xFFFF0000u);
}

__device__ __forceinline__ unsigned short f2bf1(float a) {
    unsigned u = __float_as_uint(a);
    u += 0x7FFF + ((u >> 16) & 1);
    return (unsigned short)(u >> 16);
}

__device__ __forceinline__ float act_leaky_elu(float v) {
    float l = (v >= 0.0f) ? v : 0.01f * v;
    return (l > 0.0f) ? l : expm1f(l);
}

__device__ __forceinline__ int get_xcd() {
    int x;
    asm volatile("s_getreg_b32 %0, hwreg(HW_REG_XCC_ID, 0, 4)" : "=s"(x));
    return x & 7;
}

// B-fragment for mfma_16x16x32_bf16 from fp32 W[k][n] (row-major [128][128]).
__device__ __forceinline__ short8 load_bfrag(const float* __restrict__ W,
                                             int n, int k0) {
    union { short8 s8; unsigned u[4]; } r;
    #pragma unroll
    for (int j = 0; j < 4; ++j) {
        float a = W[(k0 + 2 * j) * 128 + n];
        float b = W[(k0 + 2 * j + 1) * 128 + n];
        r.u[j] = f2bf_pack(a, b);
    }
    return r.s8;
}

__device__ __forceinline__ short8 load_afrag_f32(const float* __restrict__ p) {
    float4 a = ((const float4*)p)[0];
    float4 b = ((const float4*)p)[1];
    union { short8 s8; unsigned u[4]; } r;
    r.u[0] = f2bf_pack(a.x, a.y); r.u[1] = f2bf_pack(a.z, a.w);
    r.u[2] = f2bf_pack(b.x, b.y); r.u[3] = f2bf_pack(b.z, b.w);
    return r.s8;
}

// ---------------- shared GEMM body: hb = bf16(x @ Wpre + bpre) ----------------
__device__ __forceinline__ void gemm_pre(const float* __restrict__ x,
                                         const float* __restrict__ Wpre,
                                         const float* __restrict__ bpre,
                                         unsigned short* __restrict__ hb,
                                         int N) {
    const int lane = threadIdx.x & 63;
    const int wv = threadIdx.x >> 6;
    const int q = lane >> 4;
    const int m = lane & 15;
    const int cg = wv * 32;
    short8 B[2][4];
    #pragma unroll
    for (int ct = 0; ct < 2; ++ct)
        #pragma unroll
        for (int c = 0; c < 4; ++c)
            B[ct][c] = load_bfrag(Wpre, cg + ct * 16 + m, c * 32 + q * 8);
    const float b0 = bpre[cg + m];
    const float b1 = bpre[cg + 16 + m];
    const int rb = blockIdx.x * 128;
    #pragma unroll 2
    for (int rt = 0; rt < 8; ++rt) {
        int row = rb + rt * 16 + m;
        int rc = min(row, N - 1);
        const float* xp = x + (size_t)rc * 128 + q * 8;
        float4v a0 = {0.f, 0.f, 0.f, 0.f}, a1 = {0.f, 0.f, 0.f, 0.f};
        #pragma unroll
        for (int c = 0; c < 4; ++c) {
            short8 a = load_afrag_f32(xp + c * 32);
            a0 = __builtin_amdgcn_mfma_f32_16x16x32_bf16(a, B[0][c], a0, 0, 0, 0);
            a1 = __builtin_amdgcn_mfma_f32_16x16x32_bf16(a, B[1][c], a1, 0, 0, 0);
        }
        #pragma unroll
        for (int r = 0; r < 4; ++r) {
            int ro = rb + rt * 16 + q * 4 + r;
            if (ro < N) {
                hb[(size_t)ro * 128 + cg + m]      = f2bf1(a0[r] + b0);
                hb[(size_t)ro * 128 + cg + 16 + m] = f2bf1(a1[r] + b1);
            }
        }
    }
}

// ---------------- fused GEMM + XCD-local counting (packed path) ---------------
__global__ __launch_bounds__(256)
void k_pre_cntX(const float* __restrict__ x, const float* __restrict__ Wpre,
                const float* __restrict__ bpre, unsigned short* __restrict__ hb,
                int N, int gd,
                const int* __restrict__ ei, const float* __restrict__ ew,
                unsigned long long* __restrict__ cnt8,
                unsigned* __restrict__ aux, int E) {
    if ((int)blockIdx.x >= gd) {
        const int xcd = get_xcd();
        unsigned long long* slice = cnt8 + (size_t)xcd * N;  // private 8B*N slice
        const int stride = ((int)gridDim.x - gd) * 256;
        for (int e = ((int)blockIdx.x - gd) * 256 + (int)threadIdx.x; e < E;
             e += stride) {
            const int col = ei[E + e];
            const unsigned wq =
                (unsigned)__builtin_rintf(ew[e] * WQ_SCALE) & 0x7FFFu;
            unsigned long long old = __hip_atomic_fetch_add(
                &slice[col], (1ULL << 32) | (unsigned long long)wq,
                __ATOMIC_RELAXED, __HIP_MEMORY_SCOPE_WORKGROUP);
            aux[e] = ((unsigned)(old >> 32) << 18) | ((unsigned)xcd << 15) | wq;
        }
        return;
    }
    gemm_pre(x, Wpre, bpre, hb, N);
}

// ---------------- fused GEMM + device-atomic counting (fallback) --------------
__global__ __launch_bounds__(256)
void k_pre_cntD(const float* __restrict__ x, const float* __restrict__ Wpre,
                const float* __restrict__ bpre, unsigned short* __restrict__ hb,
                int N, int gd,
                const int* __restrict__ ei, int* __restrict__ cnti,
                int* __restrict__ rank, int E) {
    if ((int)blockIdx.x >= gd) {
        const int stride = ((int)gridDim.x - gd) * 256;
        for (int e = ((int)blockIdx.x - gd) * 256 + (int)threadIdx.x; e < E;
             e += stride) {
            rank[e] = atomicAdd(&cnti[ei[E + e]], 1);
        }
        return;
    }
    gemm_pre(x, Wpre, bpre, hb, N);
}

// ---------------- per-node: totals, dis, per-XCD exclusive bases --------------
__global__ __launch_bounds__(256)
void k_base(const unsigned long long* __restrict__ cnt8,
            unsigned* __restrict__ bas, float* __restrict__ dis,
            int* __restrict__ cti, int N) {
    int n = blockIdx.x * 256 + threadIdx.x;
    if (blockIdx.x == 0 && threadIdx.x == 0) cti[N] = 0;
    if (n >= N) return;
    unsigned b = 0;
    unsigned long long sw = 0;
    unsigned bb[8];
    #pragma unroll
    for (int xx = 0; xx < 8; ++xx) {
        unsigned long long c = cnt8[(size_t)xx * N + n];
        bb[xx] = b;
        b += (unsigned)(c >> 32);
        sw += (c & 0xFFFFFFFFULL);
    }
    ((uint4*)(bas + (size_t)n * 8))[0] = make_uint4(bb[0], bb[1], bb[2], bb[3]);
    ((uint4*)(bas + (size_t)n * 8))[1] = make_uint4(bb[4], bb[5], bb[6], bb[7]);
    cti[n] = (int)b;
    float d = (float)sw * WQ_INV;
    dis[n] = (d > 0.0f) ? (1.0f / sqrtf(fmaxf(d, 1e-12f))) : 0.0f;
}

// ---------------- scans (block-sum add folded into consumers) -----------------
__global__ __launch_bounds__(256)
void k_scan1(const int* __restrict__ in, int* __restrict__ out,
             int* __restrict__ blksum, int n) {
    __shared__ int sh[256];
    const int tid = threadIdx.x;
    const int idx = blockIdx.x * 1024 + tid * 4;
    int v0 = (idx + 0 < n) ? in[idx + 0] : 0;
    int v1 = (idx + 1 < n) ? in[idx + 1] : 0;
    int v2 = (idx + 2 < n) ? in[idx + 2] : 0;
    int v3 = (idx + 3 < n) ? in[idx + 3] : 0;
    int tsum = v0 + v1 + v2 + v3;
    sh[tid] = tsum;
    __syncthreads();
    #pragma unroll
    for (int off = 1; off < 256; off <<= 1) {
        int add = (tid >= off) ? sh[tid - off] : 0;
        __syncthreads();
        sh[tid] += add;
        __syncthreads();
    }
    int excl = sh[tid] - tsum;
    if (idx + 0 < n) out[idx + 0] = excl;
    if (idx + 1 < n) out[idx + 1] = excl + v0;
    if (idx + 2 < n) out[idx + 2] = excl + v0 + v1;
    if (idx + 3 < n) out[idx + 3] = excl + v0 + v1 + v2;
    if (tid == 255) blksum[blockIdx.x] = sh[255];
}

__global__ __launch_bounds__(128)
void k_scan2(int* __restrict__ blksum, int nb) {
    __shared__ int sh[128];
    const int tid = threadIdx.x;
    int orig = (tid < nb) ? blksum[tid] : 0;
    sh[tid] = orig;
    __syncthreads();
    #pragma unroll
    for (int off = 1; off < 128; off <<= 1) {
        int add = (tid >= off) ? sh[tid - off] : 0;
        __syncthreads();
        sh[tid] += add;
        __syncthreads();
    }
    if (tid < nb) blksum[tid] = sh[tid] - orig;
}

// ---------------- scatter into CSR (packed): pos = rowp+base[xcd]+rank --------
__global__ __launch_bounds__(256)
void k_scatter8(const int* __restrict__ ei, const unsigned* __restrict__ aux,
                const int* __restrict__ rowp, const int* __restrict__ blks,
                const unsigned* __restrict__ bas, unsigned* __restrict__ recs,
                int E) {
    int e = blockIdx.x * 256 + threadIdx.x;
    if (e >= E) return;
    unsigned a = aux[e];
    int col = ei[E + e];
    int pos = rowp[col] + blks[col >> 10] +
              (int)bas[(size_t)col * 8 + ((a >> 15) & 7u)] + (int)(a >> 18);
    recs[pos] = ((a & 0x7FFFu) << 17) | (unsigned)ei[e];
}

// ---------------- fallback scatter + degsum (wide recs) -----------------------
__global__ __launch_bounds__(256)
void k_scatterW(const int* __restrict__ ei, const float* __restrict__ ew,
                const int* __restrict__ rowp, const int* __restrict__ blks,
                const int* __restrict__ rank, int2* __restrict__ recs, int E) {
    int e = blockIdx.x * 256 + threadIdx.x;
    if (e < E) {
        int c = ei[E + e];
        int pos = rowp[c] + blks[c >> 10] + rank[e];
        recs[pos] = make_int2(ei[e], __float_as_int(ew[e]));
    }
}

__global__ __launch_bounds__(256)
void k_degsumW(const int* __restrict__ rowp, const int* __restrict__ blks,
               const int2* __restrict__ recs, float* __restrict__ dis, int N) {
    int n = blockIdx.x * 256 + threadIdx.x;
    if (n >= N) return;
    int s  = rowp[n] + blks[n >> 10];
    int eE = rowp[n + 1] + blks[(n + 1) >> 10];
    float d = 0.0f;
    for (int e = s; e < eE; ++e) d += __int_as_float(recs[e].y);
    dis[n] = (d > 0.0f) ? (1.0f / sqrtf(fmaxf(d, 1e-12f))) : 0.0f;
}

// ---------------- pull aggregation: quarter-wave rows, 4 edges/iter -----------
template <bool PACKED>
__global__ __launch_bounds__(256)
void k_pull(const int* __restrict__ rowp, const int* __restrict__ blks,
            const void* __restrict__ recs_, const float* __restrict__ dis,
            const uint4* __restrict__ hb4, uint4* __restrict__ agb4,
            uint4* __restrict__ mnb4, int N) {
    const int node = blockIdx.x * 4 + (threadIdx.x >> 6);
    if (node >= N) return;
    const int lane = threadIdx.x & 63;
    const int q4 = lane >> 4;          // quarter: which edge of the group of 4
    const int sub = lane & 15;         // uint4 index within the 16-uint4 row
    int s  = __builtin_amdgcn_readfirstlane(rowp[node] + blks[node >> 10]);
    int eE = __builtin_amdgcn_readfirstlane(rowp[node + 1] +
                                            blks[(node + 1) >> 10]);
    const float dcol = dis[node];
    const float im = 1.0f / fmaxf((float)(eE - s), 1.0f);

    float aA[8], aM[8];
    #pragma unroll
    for (int i = 0; i < 8; ++i) { aA[i] = 0.f; aM[i] = 0.f; }

    #pragma unroll 2
    for (int e = s; e < eE; e += 4) {
        int el = e + q4;
        bool ok = el < eE;
        int el2 = ok ? el : (eE - 1);
        int src; float w;
        if (PACKED) {
            unsigned rv = ((const unsigned*)recs_)[el2];
            src = (int)(rv & 0x1FFFFu);
            w = (float)(rv >> 17) * WQ_INV;
        } else {
            int2 rv = ((const int2*)recs_)[el2];
            src = rv.x;
            w = __int_as_float(rv.y);
        }
        if (!ok) w = 0.f;
        float c = dis[src] * w;
        uint4 u = hb4[(size_t)src * 16 + sub];
        float f0 = __uint_as_float(u.x << 16);
        float f1 = __uint_as_float(u.x & 0xFFFF0000u);
        float f2 = __uint_as_float(u.y << 16);
        float f3 = __uint_as_float(u.y & 0xFFFF0000u);
        float f4 = __uint_as_float(u.z << 16);
        float f5 = __uint_as_float(u.z & 0xFFFF0000u);
        float f6 = __uint_as_float(u.w << 16);
        float f7 = __uint_as_float(u.w & 0xFFFF0000u);
        aA[0] = fmaf(c, f0, aA[0]); aM[0] = fmaf(w, f0, aM[0]);
        aA[1] = fmaf(c, f1, aA[1]); aM[1] = fmaf(w, f1, aM[1]);
        aA[2] = fmaf(c, f2, aA[2]); aM[2] = fmaf(w, f2, aM[2]);
        aA[3] = fmaf(c, f3, aA[3]); aM[3] = fmaf(w, f3, aM[3]);
        aA[4] = fmaf(c, f4, aA[4]); aM[4] = fmaf(w, f4, aM[4]);
        aA[5] = fmaf(c, f5, aA[5]); aM[5] = fmaf(w, f5, aM[5]);
        aA[6] = fmaf(c, f6, aA[6]); aM[6] = fmaf(w, f6, aM[6]);
        aA[7] = fmaf(c, f7, aA[7]); aM[7] = fmaf(w, f7, aM[7]);
    }

    #pragma unroll
    for (int i = 0; i < 8; ++i) {
        aA[i] += __shfl_xor(aA[i], 32, 64);
        aA[i] += __shfl_xor(aA[i], 16, 64);
        aM[i] += __shfl_xor(aM[i], 32, 64);
        aM[i] += __shfl_xor(aM[i], 16, 64);
    }

    if (q4 == 0) {
        uint4 o;
        o.x = f2bf_pack(aA[0] * dcol, aA[1] * dcol);
        o.y = f2bf_pack(aA[2] * dcol, aA[3] * dcol);
        o.z = f2bf_pack(aA[4] * dcol, aA[5] * dcol);
        o.w = f2bf_pack(aA[6] * dcol, aA[7] * dcol);
        agb4[(size_t)node * 16 + sub] = o;
    } else if (q4 == 1) {
        uint4 o;
        o.x = f2bf_pack(aM[0] * im, aM[1] * im);
        o.y = f2bf_pack(aM[2] * im, aM[3] * im);
        o.z = f2bf_pack(aM[4] * im, aM[5] * im);
        o.w = f2bf_pack(aM[6] * im, aM[7] * im);
        mnb4[(size_t)node * 16 + sub] = o;
    }
}

// ---------------- fused epilogue: both output halves, hb read once ------------
// 512 threads: waves 0-3 ARMA (relu), waves 4-7 SAGE (leaky+elu).
__global__ __launch_bounds__(512)
void k_final2(const unsigned short* __restrict__ agb,
              const unsigned short* __restrict__ mnb,
              const unsigned short* __restrict__ hb,
              const float* __restrict__ Wai, const float* __restrict__ War,
              const float* __restrict__ ab,
              const float* __restrict__ Wsl, const float* __restrict__ Wsr,
              const float* __restrict__ bsl,
              float* __restrict__ out, int N) {
    const int lane = threadIdx.x & 63;
    const int wv = threadIdx.x >> 6;           // 0..7
    const bool sg = wv >= 4;
    const int q = lane >> 4;
    const int m = lane & 15;
    const int cg = (wv & 3) * 32;
    const unsigned short* A1 = sg ? mnb : agb;
    const float* W1 = sg ? Wsl : Wai;
    const float* W2 = sg ? Wsr : War;
    const float* bias = sg ? bsl : ab;
    float* op = out + (sg ? 128 : 0);
    short8 B1[2][4], B2[2][4];
    #pragma unroll
    for (int ct = 0; ct < 2; ++ct)
        #pragma unroll
        for (int c = 0; c < 4; ++c) {
            B1[ct][c] = load_bfrag(W1, cg + ct * 16 + m, c * 32 + q * 8);
            B2[ct][c] = load_bfrag(W2, cg + ct * 16 + m, c * 32 + q * 8);
        }
    const float b0 = bias[cg + m];
    const float b1 = bias[cg + 16 + m];
    const int rb = blockIdx.x * 128;
    #pragma unroll 2
    for (int rt = 0; rt < 8; ++rt) {
        int row = rb + rt * 16 + m;
        int rc = min(row, N - 1);
        const short8* a1 = (const short8*)(A1 + (size_t)rc * 128 + q * 8);
        const short8* a2 = (const short8*)(hb + (size_t)rc * 128 + q * 8);
        float4v c0 = {0.f, 0.f, 0.f, 0.f}, c1 = {0.f, 0.f, 0.f, 0.f};
        #pragma unroll
        for (int c = 0; c < 4; ++c) {
            short8 a = a1[c * 4];
            c0 = __builtin_amdgcn_mfma_f32_16x16x32_bf16(a, B1[0][c], c0, 0, 0, 0);
            c1 = __builtin_amdgcn_mfma_f32_16x16x32_bf16(a, B1[1][c], c1, 0, 0, 0);
        }
        #pragma unroll
        for (int c = 0; c < 4; ++c) {
            short8 a = a2[c * 4];
            c0 = __builtin_amdgcn_mfma_f32_16x16x32_bf16(a, B2[0][c], c0, 0, 0, 0);
            c1 = __builtin_amdgcn_mfma_f32_16x16x32_bf16(a, B2[1][c], c1, 0, 0, 0);
        }
        #pragma unroll
        for (int r = 0; r < 4; ++r) {
            int ro = rb + rt * 16 + q * 4 + r;
            if (ro < N) {
                float v0 = c0[r] + b0;
                float v1 = c1[r] + b1;
                if (!sg) { v0 = fmaxf(v0, 0.f); v1 = fmaxf(v1, 0.f); }
                else     { v0 = act_leaky_elu(v0); v1 = act_leaky_elu(v1); }
                op[(size_t)ro * 256 + cg + m]      = v0;
                op[(size_t)ro * 256 + cg + 16 + m] = v1;
            }
        }
    }
}

extern "C" void kernel_launch(void* const* d_in, const int* in_sizes, int n_in,
                              void* d_out, int out_size, void* d_ws, size_t ws_size,
                              hipStream_t stream) {
    const float* x    = (const float*)d_in[0];
    const int*   ei   = (const int*)d_in[1];
    const float* ew   = (const float*)d_in[2];
    const float* Wpre = (const float*)d_in[3];
    const float* bpre = (const float*)d_in[4];
    const float* Wai  = (const float*)d_in[5];
    const float* War  = (const float*)d_in[6];
    const float* ab   = (const float*)d_in[7];
    const float* Wsl  = (const float*)d_in[8];
    const float* bsl  = (const float*)d_in[9];
    const float* Wsr  = (const float*)d_in[10];

    const int N = in_sizes[0] / 128;
    const int E = in_sizes[2];
    const size_t NF = (size_t)N * 128;
    const bool packed = (N <= (1 << 17));

    // workspace (256-B aligned blocks); overlays:
    //   bas (N*32 B) on mnb head: dead before k_pull writes mnb
    //   recs on cnt8: cnt8 dead after k_base
    char* p = (char*)d_ws;
    auto take = [&p](size_t bytes) {
        char* r = p;
        p += (bytes + 255) & ~(size_t)255;
        return r;
    };
    unsigned short* hb  = (unsigned short*)take(NF * 2);
    unsigned short* agb = (unsigned short*)take(NF * 2);
    unsigned short* mnb = (unsigned short*)take(NF * 2);
    unsigned* bas = (unsigned*)mnb;                    // overlay (N*32 <= NF*2)
    float* dis  = (float*)take((size_t)N * 4);
    int*   cti  = (int*)take((size_t)(N + 1) * 4);
    int*   rowp = (int*)take((size_t)(N + 1) * 4);
    int*   blks = (int*)take(128 * 4);
    unsigned* aux = (unsigned*)take((size_t)E * 4);    // packed: rank|xcd|wq
    size_t crBytes = (size_t)N * 64;
    size_t recsBytes = packed ? (size_t)E * 4 : (size_t)E * 8;
    if (recsBytes > crBytes) crBytes = recsBytes;
    char* crp = take(crBytes);
    unsigned long long* cnt8 = (unsigned long long*)crp;
    void*               recs = (void*)crp;

    const int gd = (N + 127) / 128;
    const int ge = (E + 255) / 256;
    const int gv = (N + 255) / 256;
    const int CB = 2048;                 // counting blocks in fused dispatch
    const int ns = N + 1;
    const int nb = (ns + 1023) / 1024;   // <=128 blocks (N <= 131071 on bench)

    if (packed) {
        hipMemsetAsync(cnt8, 0, (size_t)N * 64, stream);
        k_pre_cntX<<<gd + CB, 256, 0, stream>>>(x, Wpre, bpre, hb, N, gd,
                                                ei, ew, cnt8, aux, E);
        k_base<<<gv, 256, 0, stream>>>(cnt8, bas, dis, cti, N);
        k_scan1<<<nb, 256, 0, stream>>>(cti, rowp, blks, ns);
        k_scan2<<<1, 128, 0, stream>>>(blks, nb);
        k_scatter8<<<ge, 256, 0, stream>>>(ei, aux, rowp, blks, bas,
                                           (unsigned*)recs, E);
        k_pull<true><<<(N + 3) / 4, 256, 0, stream>>>(rowp, blks, recs, dis,
            (const uint4*)hb, (uint4*)agb, (uint4*)mnb, N);
    } else {
        hipMemsetAsync(cti, 0, (size_t)(N + 1) * 4, stream);
        k_pre_cntD<<<gd + CB, 256, 0, stream>>>(x, Wpre, bpre, hb, N, gd,
                                                ei, cti, (int*)aux, E);
        k_scan1<<<nb, 256, 0, stream>>>(cti, rowp, blks, ns);
        k_scan2<<<1, 128, 0, stream>>>(blks, nb);
        k_scatterW<<<ge, 256, 0, stream>>>(ei, ew, rowp, blks, (int*)aux,
                                           (int2*)recs, E);
        k_degsumW<<<gv, 256, 0, stream>>>(rowp, blks, (const int2*)recs, dis, N);
        k_pull<false><<<(N + 3) / 4, 256, 0, stream>>>(rowp, blks, recs, dis,
            (const uint4*)hb, (uint4*)agb, (uint4*)mnb, N);
    }

    k_final2<<<gd, 512, 0, stream>>>(agb, mnb, hb, Wai, War, ab,
                                     Wsl, Wsr, bsl, (float*)d_out, N);
}

// Round 5
// 383.270 us; speedup vs baseline: 1.1293x; 1.1293x over previous
//
#include <hip/hip_runtime.h>
#include <math.h>

// ---------------------------------------------------------------------------
// N=100000, E=1600000, dims 128. Round 11:
//  JOURNAL: r10 REFUTED XCD-local atomics (scope/layout do NOT remove the
//  ~32 B/op atomic write-through; WRITE_SIZE stayed 82 MB, pass got slower).
//  => eliminate per-edge global atomics entirely: LDS-binned counting sort.
//   - kBin1 (fused w/ GEMM): LDS histogram over 782 buckets (col>>7),
//     aux[e] = per-(block,bucket) rank; flush = 200K atomics on 782 hot
//     lines (cheap) instead of 1.6M on 100K lines.
//   - k_scan1 (1 block) over gcnt -> gbase.
//   - kBin2: scatter 8-B records into bucket segments; each block writes
//     contiguous per-bucket runs -> XCD-private dirty lines, no bounce.
//   - kBktCsr: one block/bucket: LDS per-col count + u64 wq-sum (-> dis,
//     k_degsum eliminated), LDS scan -> absolute rowp, LDS-rank scatter ->
//     col-sorted recs. All per-edge RMWs in LDS.
//   - k_pull reads absolute rowp (template ABS); k_final2 unchanged.
//   - Overlays: binned on agb, aux+bbase on mnb (dead before k_pull writes).
//   - Fallback N > 130944: proven r9 pipeline (device atomics).
// ---------------------------------------------------------------------------

typedef __attribute__((ext_vector_type(8))) short short8;   // 8 bf16 (4 VGPR)
typedef __attribute__((ext_vector_type(4))) float float4v;  // 4 fp32 acc

#define WQ_SCALE 32767.0f
#define WQ_INV   (1.0f / 32767.0f)
#define NB_BIN   256   // counting/scatter blocks (must match kBin1<->kBin2)

__device__ __forceinline__ unsigned f2bf_pack(float a, float b) {
    unsigned ua = __float_as_uint(a);
    unsigned ub = __float_as_uint(b);
    ua += 0x7FFF + ((ua >> 16) & 1);   // RNE
    ub += 0x7FFF + ((ub >> 16) & 1);
    return (ua >> 16) | (ub & 0xFFFF0000u);
}

__device__ __forceinline__ unsigned short f2bf1(float a) {
    unsigned u = __float_as_uint(a);
    u += 0x7FFF + ((u >> 16) & 1);
    return (unsigned short)(u >> 16);
}

__device__ __forceinline__ float act_leaky_elu(float v) {
    float l = (v >= 0.0f) ? v : 0.01f * v;
    return (l > 0.0f) ? l : expm1f(l);
}

// B-fragment for mfma_16x16x32_bf16 from fp32 W[k][n] (row-major [128][128]).
__device__ __forceinline__ short8 load_bfrag(const float* __restrict__ W,
                                             int n, int k0) {
    union { short8 s8; unsigned u[4]; } r;
    #pragma unroll
    for (int j = 0; j < 4; ++j) {
        float a = W[(k0 + 2 * j) * 128 + n];
        float b = W[(k0 + 2 * j + 1) * 128 + n];
        r.u[j] = f2bf_pack(a, b);
    }
    return r.s8;
}

__device__ __forceinline__ short8 load_afrag_f32(const float* __restrict__ p) {
    float4 a = ((const float4*)p)[0];
    float4 b = ((const float4*)p)[1];
    union { short8 s8; unsigned u[4]; } r;
    r.u[0] = f2bf_pack(a.x, a.y); r.u[1] = f2bf_pack(a.z, a.w);
    r.u[2] = f2bf_pack(b.x, b.y); r.u[3] = f2bf_pack(b.z, b.w);
    return r.s8;
}

// ---------------- shared GEMM body: hb = bf16(x @ Wpre + bpre) ----------------
__device__ __forceinline__ void gemm_pre(const float* __restrict__ x,
                                         const float* __restrict__ Wpre,
                                         const float* __restrict__ bpre,
                                         unsigned short* __restrict__ hb,
                                         int N) {
    const int lane = threadIdx.x & 63;
    const int wv = threadIdx.x >> 6;
    const int q = lane >> 4;
    const int m = lane & 15;
    const int cg = wv * 32;
    short8 B[2][4];
    #pragma unroll
    for (int ct = 0; ct < 2; ++ct)
        #pragma unroll
        for (int c = 0; c < 4; ++c)
            B[ct][c] = load_bfrag(Wpre, cg + ct * 16 + m, c * 32 + q * 8);
    const float b0 = bpre[cg + m];
    const float b1 = bpre[cg + 16 + m];
    const int rb = blockIdx.x * 128;
    #pragma unroll 2
    for (int rt = 0; rt < 8; ++rt) {
        int row = rb + rt * 16 + m;
        int rc = min(row, N - 1);
        const float* xp = x + (size_t)rc * 128 + q * 8;
        float4v a0 = {0.f, 0.f, 0.f, 0.f}, a1 = {0.f, 0.f, 0.f, 0.f};
        #pragma unroll
        for (int c = 0; c < 4; ++c) {
            short8 a = load_afrag_f32(xp + c * 32);
            a0 = __builtin_amdgcn_mfma_f32_16x16x32_bf16(a, B[0][c], a0, 0, 0, 0);
            a1 = __builtin_amdgcn_mfma_f32_16x16x32_bf16(a, B[1][c], a1, 0, 0, 0);
        }
        #pragma unroll
        for (int r = 0; r < 4; ++r) {
            int ro = rb + rt * 16 + q * 4 + r;
            if (ro < N) {
                hb[(size_t)ro * 128 + cg + m]      = f2bf1(a0[r] + b0);
                hb[(size_t)ro * 128 + cg + 16 + m] = f2bf1(a1[r] + b1);
            }
        }
    }
}

// ---------------- fused GEMM + LDS-binned bucket count (packed path) ----------
// Blocks [0, gd): GEMM. Blocks [gd, gd+NB_BIN): per-block LDS histogram over
// buckets (col>>7); aux[e] = local rank; flush to gcnt + bbase.
__global__ __launch_bounds__(256)
void k_pre_bin1(const float* __restrict__ x, const float* __restrict__ Wpre,
                const float* __restrict__ bpre, unsigned short* __restrict__ hb,
                int N, int gd,
                const int* __restrict__ ei, int* __restrict__ gcnt,
                unsigned* __restrict__ aux, int* __restrict__ bbase,
                int E, int NBKT) {
    __shared__ int hist[1024];
    if ((int)blockIdx.x >= gd) {
        const int cb = (int)blockIdx.x - gd;
        const int tid = threadIdx.x;
        for (int j = tid; j < NBKT; j += 256) hist[j] = 0;
        __syncthreads();
        const int stride = NB_BIN * 256;
        for (int e = cb * 256 + tid; e < E; e += stride) {
            int col = ei[E + e];
            aux[e] = (unsigned)atomicAdd(&hist[col >> 7], 1);
        }
        __syncthreads();
        for (int j = tid; j < NBKT; j += 256) {
            int h = hist[j];
            int bb = (h > 0) ? atomicAdd(&gcnt[j], h) : 0;
            bbase[cb * 1024 + j] = bb;
        }
        return;
    }
    gemm_pre(x, Wpre, bpre, hb, N);
}

// ---------------- fused GEMM + device-atomic counting (fallback) --------------
__global__ __launch_bounds__(256)
void k_pre_cntD(const float* __restrict__ x, const float* __restrict__ Wpre,
                const float* __restrict__ bpre, unsigned short* __restrict__ hb,
                int N, int gd,
                const int* __restrict__ ei, int* __restrict__ cnti,
                int* __restrict__ rank, int E) {
    if ((int)blockIdx.x >= gd) {
        const int stride = ((int)gridDim.x - gd) * 256;
        for (int e = ((int)blockIdx.x - gd) * 256 + (int)threadIdx.x; e < E;
             e += stride) {
            rank[e] = atomicAdd(&cnti[ei[E + e]], 1);
        }
        return;
    }
    gemm_pre(x, Wpre, bpre, hb, N);
}

// ---------------- scans -------------------------------------------------------
__global__ __launch_bounds__(256)
void k_scan1(const int* __restrict__ in, int* __restrict__ out,
             int* __restrict__ blksum, int n) {
    __shared__ int sh[256];
    const int tid = threadIdx.x;
    const int idx = blockIdx.x * 1024 + tid * 4;
    int v0 = (idx + 0 < n) ? in[idx + 0] : 0;
    int v1 = (idx + 1 < n) ? in[idx + 1] : 0;
    int v2 = (idx + 2 < n) ? in[idx + 2] : 0;
    int v3 = (idx + 3 < n) ? in[idx + 3] : 0;
    int tsum = v0 + v1 + v2 + v3;
    sh[tid] = tsum;
    __syncthreads();
    #pragma unroll
    for (int off = 1; off < 256; off <<= 1) {
        int add = (tid >= off) ? sh[tid - off] : 0;
        __syncthreads();
        sh[tid] += add;
        __syncthreads();
    }
    int excl = sh[tid] - tsum;
    if (idx + 0 < n) out[idx + 0] = excl;
    if (idx + 1 < n) out[idx + 1] = excl + v0;
    if (idx + 2 < n) out[idx + 2] = excl + v0 + v1;
    if (idx + 3 < n) out[idx + 3] = excl + v0 + v1 + v2;
    if (tid == 255) blksum[blockIdx.x] = sh[255];
}

__global__ __launch_bounds__(128)
void k_scan2(int* __restrict__ blksum, int nb) {
    __shared__ int sh[128];
    const int tid = threadIdx.x;
    int orig = (tid < nb) ? blksum[tid] : 0;
    sh[tid] = orig;
    __syncthreads();
    #pragma unroll
    for (int off = 1; off < 128; off <<= 1) {
        int add = (tid >= off) ? sh[tid - off] : 0;
        __syncthreads();
        sh[tid] += add;
        __syncthreads();
    }
    if (tid < nb) blksum[tid] = sh[tid] - orig;
}

// ---------------- bin scatter: 8-B records into bucket segments ---------------
__global__ __launch_bounds__(256)
void k_bin2(const int* __restrict__ ei, const float* __restrict__ ew,
            const unsigned* __restrict__ aux, const int* __restrict__ gbase,
            const int* __restrict__ bbase, uint2* __restrict__ binned,
            int E, int NBKT) {
    __shared__ int base[1024];
    const int cb = blockIdx.x;
    const int tid = threadIdx.x;
    for (int j = tid; j < NBKT; j += 256)
        base[j] = gbase[j] + bbase[cb * 1024 + j];
    __syncthreads();
    const int stride = NB_BIN * 256;
    for (int e = cb * 256 + tid; e < E; e += stride) {
        int col = ei[E + e];
        int src = ei[e];
        unsigned wq = (unsigned)__builtin_rintf(ew[e] * WQ_SCALE) & 0x7FFFu;
        int pos = base[col >> 7] + (int)aux[e];
        binned[pos] = make_uint2((wq << 17) | (unsigned)src, (unsigned)col);
    }
}

// ---------------- per-bucket CSR finalize: rowp, dis, sorted recs -------------
__global__ __launch_bounds__(256)
void k_bktcsr(const uint2* __restrict__ binned, const int* __restrict__ gbase,
              unsigned* __restrict__ recs, int* __restrict__ rowp,
              float* __restrict__ dis, int N, int E) {
    __shared__ int cnt[128];
    __shared__ int colbase[128];
    __shared__ unsigned long long wsum[128];
    const int bkt = blockIdx.x;
    const int tid = threadIdx.x;
    if (tid < 128) { cnt[tid] = 0; wsum[tid] = 0ULL; }
    __syncthreads();
    const int s = gbase[bkt], e = gbase[bkt + 1];
    for (int i = s + tid; i < e; i += 256) {
        uint2 r = binned[i];
        int cl = (int)(r.y & 127u);
        atomicAdd(&cnt[cl], 1);
        atomicAdd(&wsum[cl], (unsigned long long)(r.x >> 17));
    }
    __syncthreads();
    if (tid < 128) colbase[tid] = cnt[tid];
    __syncthreads();
    #pragma unroll
    for (int off = 1; off < 128; off <<= 1) {
        int add = 0;
        if (tid < 128 && tid >= off) add = colbase[tid - off];
        __syncthreads();
        if (tid < 128) colbase[tid] += add;
        __syncthreads();
    }
    if (tid < 128) {
        colbase[tid] = s + colbase[tid] - cnt[tid];   // absolute col base
        int node = bkt * 128 + tid;
        if (node < N) {
            rowp[node] = colbase[tid];
            float d = (float)wsum[tid] * WQ_INV;
            dis[node] = (wsum[tid] > 0ULL)
                          ? (1.0f / sqrtf(fmaxf(d, 1e-12f))) : 0.0f;
        }
        cnt[tid] = 0;
    }
    if (bkt == 0 && tid == 0) rowp[N] = E;
    __syncthreads();
    for (int i = s + tid; i < e; i += 256) {
        uint2 r = binned[i];
        int cl = (int)(r.y & 127u);
        int rk = atomicAdd(&cnt[cl], 1);
        recs[colbase[cl] + rk] = r.x;
    }
}

// ---------------- fallback scatter + degsum (wide recs) -----------------------
__global__ __launch_bounds__(256)
void k_scatterW(const int* __restrict__ ei, const float* __restrict__ ew,
                const int* __restrict__ rowp, const int* __restrict__ blks,
                const int* __restrict__ rank, int2* __restrict__ recs, int E) {
    int e = blockIdx.x * 256 + threadIdx.x;
    if (e < E) {
        int c = ei[E + e];
        int pos = rowp[c] + blks[c >> 10] + rank[e];
        recs[pos] = make_int2(ei[e], __float_as_int(ew[e]));
    }
}

__global__ __launch_bounds__(256)
void k_degsumW(const int* __restrict__ rowp, const int* __restrict__ blks,
               const int2* __restrict__ recs, float* __restrict__ dis, int N) {
    int n = blockIdx.x * 256 + threadIdx.x;
    if (n >= N) return;
    int s  = rowp[n] + blks[n >> 10];
    int eE = rowp[n + 1] + blks[(n + 1) >> 10];
    float d = 0.0f;
    for (int e = s; e < eE; ++e) d += __int_as_float(recs[e].y);
    dis[n] = (d > 0.0f) ? (1.0f / sqrtf(fmaxf(d, 1e-12f))) : 0.0f;
}

// ---------------- pull aggregation: quarter-wave rows, 4 edges/iter -----------
// ABS=true: packed u32 recs + absolute rowp. ABS=false: int2 recs + rowp+blks.
template <bool ABS>
__global__ __launch_bounds__(256)
void k_pull(const int* __restrict__ rowp, const int* __restrict__ blks,
            const void* __restrict__ recs_, const float* __restrict__ dis,
            const uint4* __restrict__ hb4, uint4* __restrict__ agb4,
            uint4* __restrict__ mnb4, int N) {
    const int node = blockIdx.x * 4 + (threadIdx.x >> 6);
    if (node >= N) return;
    const int lane = threadIdx.x & 63;
    const int q4 = lane >> 4;          // quarter: which edge of the group of 4
    const int sub = lane & 15;         // uint4 index within the 16-uint4 row
    int s, eE;
    if (ABS) {
        s  = __builtin_amdgcn_readfirstlane(rowp[node]);
        eE = __builtin_amdgcn_readfirstlane(rowp[node + 1]);
    } else {
        s  = __builtin_amdgcn_readfirstlane(rowp[node] + blks[node >> 10]);
        eE = __builtin_amdgcn_readfirstlane(rowp[node + 1] +
                                            blks[(node + 1) >> 10]);
    }
    const float dcol = dis[node];
    const float im = 1.0f / fmaxf((float)(eE - s), 1.0f);

    float aA[8], aM[8];
    #pragma unroll
    for (int i = 0; i < 8; ++i) { aA[i] = 0.f; aM[i] = 0.f; }

    #pragma unroll 2
    for (int e = s; e < eE; e += 4) {
        int el = e + q4;
        bool ok = el < eE;
        int el2 = ok ? el : (eE - 1);
        int src; float w;
        if (ABS) {
            unsigned rv = ((const unsigned*)recs_)[el2];
            src = (int)(rv & 0x1FFFFu);
            w = (float)(rv >> 17) * WQ_INV;
        } else {
            int2 rv = ((const int2*)recs_)[el2];
            src = rv.x;
            w = __int_as_float(rv.y);
        }
        if (!ok) w = 0.f;
        float c = dis[src] * w;
        uint4 u = hb4[(size_t)src * 16 + sub];
        float f0 = __uint_as_float(u.x << 16);
        float f1 = __uint_as_float(u.x & 0xFFFF0000u);
        float f2 = __uint_as_float(u.y << 16);
        float f3 = __uint_as_float(u.y & 0xFFFF0000u);
        float f4 = __uint_as_float(u.z << 16);
        float f5 = __uint_as_float(u.z & 0xFFFF0000u);
        float f6 = __uint_as_float(u.w << 16);
        float f7 = __uint_as_float(u.w & 0xFFFF0000u);
        aA[0] = fmaf(c, f0, aA[0]); aM[0] = fmaf(w, f0, aM[0]);
        aA[1] = fmaf(c, f1, aA[1]); aM[1] = fmaf(w, f1, aM[1]);
        aA[2] = fmaf(c, f2, aA[2]); aM[2] = fmaf(w, f2, aM[2]);
        aA[3] = fmaf(c, f3, aA[3]); aM[3] = fmaf(w, f3, aM[3]);
        aA[4] = fmaf(c, f4, aA[4]); aM[4] = fmaf(w, f4, aM[4]);
        aA[5] = fmaf(c, f5, aA[5]); aM[5] = fmaf(w, f5, aM[5]);
        aA[6] = fmaf(c, f6, aA[6]); aM[6] = fmaf(w, f6, aM[6]);
        aA[7] = fmaf(c, f7, aA[7]); aM[7] = fmaf(w, f7, aM[7]);
    }

    #pragma unroll
    for (int i = 0; i < 8; ++i) {
        aA[i] += __shfl_xor(aA[i], 32, 64);
        aA[i] += __shfl_xor(aA[i], 16, 64);
        aM[i] += __shfl_xor(aM[i], 32, 64);
        aM[i] += __shfl_xor(aM[i], 16, 64);
    }

    if (q4 == 0) {
        uint4 o;
        o.x = f2bf_pack(aA[0] * dcol, aA[1] * dcol);
        o.y = f2bf_pack(aA[2] * dcol, aA[3] * dcol);
        o.z = f2bf_pack(aA[4] * dcol, aA[5] * dcol);
        o.w = f2bf_pack(aA[6] * dcol, aA[7] * dcol);
        agb4[(size_t)node * 16 + sub] = o;
    } else if (q4 == 1) {
        uint4 o;
        o.x = f2bf_pack(aM[0] * im, aM[1] * im);
        o.y = f2bf_pack(aM[2] * im, aM[3] * im);
        o.z = f2bf_pack(aM[4] * im, aM[5] * im);
        o.w = f2bf_pack(aM[6] * im, aM[7] * im);
        mnb4[(size_t)node * 16 + sub] = o;
    }
}

// ---------------- fused epilogue: both output halves, hb read once ------------
// 512 threads: waves 0-3 ARMA (relu), waves 4-7 SAGE (leaky+elu).
__global__ __launch_bounds__(512)
void k_final2(const unsigned short* __restrict__ agb,
              const unsigned short* __restrict__ mnb,
              const unsigned short* __restrict__ hb,
              const float* __restrict__ Wai, const float* __restrict__ War,
              const float* __restrict__ ab,
              const float* __restrict__ Wsl, const float* __restrict__ Wsr,
              const float* __restrict__ bsl,
              float* __restrict__ out, int N) {
    const int lane = threadIdx.x & 63;
    const int wv = threadIdx.x >> 6;           // 0..7
    const bool sg = wv >= 4;
    const int q = lane >> 4;
    const int m = lane & 15;
    const int cg = (wv & 3) * 32;
    const unsigned short* A1 = sg ? mnb : agb;
    const float* W1 = sg ? Wsl : Wai;
    const float* W2 = sg ? Wsr : War;
    const float* bias = sg ? bsl : ab;
    float* op = out + (sg ? 128 : 0);
    short8 B1[2][4], B2[2][4];
    #pragma unroll
    for (int ct = 0; ct < 2; ++ct)
        #pragma unroll
        for (int c = 0; c < 4; ++c) {
            B1[ct][c] = load_bfrag(W1, cg + ct * 16 + m, c * 32 + q * 8);
            B2[ct][c] = load_bfrag(W2, cg + ct * 16 + m, c * 32 + q * 8);
        }
    const float b0 = bias[cg + m];
    const float b1 = bias[cg + 16 + m];
    const int rb = blockIdx.x * 128;
    #pragma unroll 2
    for (int rt = 0; rt < 8; ++rt) {
        int row = rb + rt * 16 + m;
        int rc = min(row, N - 1);
        const short8* a1 = (const short8*)(A1 + (size_t)rc * 128 + q * 8);
        const short8* a2 = (const short8*)(hb + (size_t)rc * 128 + q * 8);
        float4v c0 = {0.f, 0.f, 0.f, 0.f}, c1 = {0.f, 0.f, 0.f, 0.f};
        #pragma unroll
        for (int c = 0; c < 4; ++c) {
            short8 a = a1[c * 4];
            c0 = __builtin_amdgcn_mfma_f32_16x16x32_bf16(a, B1[0][c], c0, 0, 0, 0);
            c1 = __builtin_amdgcn_mfma_f32_16x16x32_bf16(a, B1[1][c], c1, 0, 0, 0);
        }
        #pragma unroll
        for (int c = 0; c < 4; ++c) {
            short8 a = a2[c * 4];
            c0 = __builtin_amdgcn_mfma_f32_16x16x32_bf16(a, B2[0][c], c0, 0, 0, 0);
            c1 = __builtin_amdgcn_mfma_f32_16x16x32_bf16(a, B2[1][c], c1, 0, 0, 0);
        }
        #pragma unroll
        for (int r = 0; r < 4; ++r) {
            int ro = rb + rt * 16 + q * 4 + r;
            if (ro < N) {
                float v0 = c0[r] + b0;
                float v1 = c1[r] + b1;
                if (!sg) { v0 = fmaxf(v0, 0.f); v1 = fmaxf(v1, 0.f); }
                else     { v0 = act_leaky_elu(v0); v1 = act_leaky_elu(v1); }
                op[(size_t)ro * 256 + cg + m]      = v0;
                op[(size_t)ro * 256 + cg + 16 + m] = v1;
            }
        }
    }
}

extern "C" void kernel_launch(void* const* d_in, const int* in_sizes, int n_in,
                              void* d_out, int out_size, void* d_ws, size_t ws_size,
                              hipStream_t stream) {
    const float* x    = (const float*)d_in[0];
    const int*   ei   = (const int*)d_in[1];
    const float* ew   = (const float*)d_in[2];
    const float* Wpre = (const float*)d_in[3];
    const float* bpre = (const float*)d_in[4];
    const float* Wai  = (const float*)d_in[5];
    const float* War  = (const float*)d_in[6];
    const float* ab   = (const float*)d_in[7];
    const float* Wsl  = (const float*)d_in[8];
    const float* bsl  = (const float*)d_in[9];
    const float* Wsr  = (const float*)d_in[10];

    const int N = in_sizes[0] / 128;
    const int E = in_sizes[2];
    const size_t NF = (size_t)N * 128;
    const int NBKT = (N + 127) >> 7;
    // packed: NBKT+1 <= 1024 (single-block scan) and src fits 17 bits
    const bool packed = (N <= 130944);

    char* p = (char*)d_ws;
    auto take = [&p](size_t bytes) {
        char* r = p;
        p += (bytes + 255) & ~(size_t)255;
        return r;
    };
    unsigned short* hb  = (unsigned short*)take(NF * 2);
    unsigned short* agb = (unsigned short*)take(NF * 2);
    unsigned short* mnb = (unsigned short*)take(NF * 2);
    unsigned* recs = (unsigned*)take(packed ? (size_t)E * 4 : (size_t)E * 8);
    int*   rowp = (int*)take((size_t)(N + 1) * 4);
    float* dis  = (float*)take((size_t)N * 4);
    int*   cti  = (int*)take((size_t)(N + 1) * 4);   // fallback count
    int*   blks = (int*)take(128 * 4);
    int*   gcnt  = (int*)take(1025 * 4);
    int*   gbase = (int*)take(1025 * 4);

    // overlays (packed path): binned on agb; aux+bbase on mnb.
    size_t binB = (size_t)E * 8;
    uint2* binned = (NF * 2 >= binB) ? (uint2*)agb : (uint2*)take(binB);
    size_t auxB = ((size_t)E * 4 + 255) & ~(size_t)255;
    size_t bbB  = (size_t)NB_BIN * 1024 * 4;
    unsigned* aux; int* bbase;
    if (NF * 2 >= auxB + bbB) {
        aux = (unsigned*)mnb;
        bbase = (int*)((char*)mnb + auxB);
    } else {
        aux = (unsigned*)take((size_t)E * 4);
        bbase = (int*)take(bbB);
    }

    const int gd = (N + 127) / 128;
    const int ge = (E + 255) / 256;
    const int gv = (N + 255) / 256;
    const int ns = N + 1;
    const int nb = (ns + 1023) / 1024;

    if (packed) {
        hipMemsetAsync(gcnt, 0, (size_t)(NBKT + 1) * 4, stream);
        k_pre_bin1<<<gd + NB_BIN, 256, 0, stream>>>(x, Wpre, bpre, hb, N, gd,
                                                    ei, gcnt, aux, bbase,
                                                    E, NBKT);
        k_scan1<<<1, 256, 0, stream>>>(gcnt, gbase, blks, NBKT + 1);
        k_bin2<<<NB_BIN, 256, 0, stream>>>(ei, ew, aux, gbase, bbase,
                                           binned, E, NBKT);
        k_bktcsr<<<NBKT, 256, 0, stream>>>(binned, gbase, recs, rowp, dis,
                                           N, E);
        k_pull<true><<<(N + 3) / 4, 256, 0, stream>>>(rowp, blks, recs, dis,
            (const uint4*)hb, (uint4*)agb, (uint4*)mnb, N);
    } else {
        hipMemsetAsync(cti, 0, (size_t)(N + 1) * 4, stream);
        k_pre_cntD<<<gd + 2048, 256, 0, stream>>>(x, Wpre, bpre, hb, N, gd,
                                                  ei, cti, (int*)aux, E);
        k_scan1<<<nb, 256, 0, stream>>>(cti, rowp, blks, ns);
        k_scan2<<<1, 128, 0, stream>>>(blks, nb);
        k_scatterW<<<ge, 256, 0, stream>>>(ei, ew, rowp, blks, (int*)aux,
                                           (int2*)recs, E);
        k_degsumW<<<gv, 256, 0, stream>>>(rowp, blks, (const int2*)recs,
                                          dis, N);
        k_pull<false><<<(N + 3) / 4, 256, 0, stream>>>(rowp, blks, recs, dis,
            (const uint4*)hb, (uint4*)agb, (uint4*)mnb, N);
    }

    k_final2<<<gd, 512, 0, stream>>>(agb, mnb, hb, Wai, War, ab,
                                     Wsl, Wsr, bsl, (float*)d_out, N);
}

// Round 6
// 373.273 us; speedup vs baseline: 1.1595x; 1.0268x over previous
//
#include <hip/hip_runtime.h>
#include <math.h>

// ---------------------------------------------------------------------------
// N=100000, E=1600000, dims 128. Round 12:
//  JOURNAL: r10 refuted XCD-local atomics; r11 LDS-binned counting sort WORKED
//  (425->383, CSR build off the top-5). Top is now k_final2 (86 us,
//  VALU 23% / Mfma 6% / HBM 21% / Occ 26% => latency-bound, ~3x headroom).
//  This round:
//   - k_prep: all 5 weight mats pre-packed to bf16 MFMA-frag layout (160 KB);
//     wave preamble becomes 16 coalesced dwordx4 loads (was 128 scalar fp32
//     loads + 64 packs, which overflowed VGPR_Count=52 -> remat/spill).
//   - k_final2: 4 independent MFMA accumulator chains (was 2 chains of 8
//     dependent), 64 rows/block (2x waves), fast ELU via __expf (was expm1f).
//   - k_bin2/k_bktcsr: gcnt scan folded in-LDS (k_scan1 dispatch removed
//     from packed path).
//  Unchanged: bin pipeline structure, k_pull, overlays, N>130944 fallback.
// ---------------------------------------------------------------------------

typedef __attribute__((ext_vector_type(8))) short short8;   // 8 bf16 (4 VGPR)
typedef __attribute__((ext_vector_type(4))) float float4v;  // 4 fp32 acc

#define WQ_SCALE 32767.0f
#define WQ_INV   (1.0f / 32767.0f)
#define NB_BIN   256   // counting/scatter blocks (must match kBin1<->kBin2)

__device__ __forceinline__ unsigned f2bf_pack(float a, float b) {
    unsigned ua = __float_as_uint(a);
    unsigned ub = __float_as_uint(b);
    ua += 0x7FFF + ((ua >> 16) & 1);   // RNE
    ub += 0x7FFF + ((ub >> 16) & 1);
    return (ua >> 16) | (ub & 0xFFFF0000u);
}

__device__ __forceinline__ unsigned short f2bf1(float a) {
    unsigned u = __float_as_uint(a);
    u += 0x7FFF + ((u >> 16) & 1);
    return (unsigned short)(u >> 16);
}

__device__ __forceinline__ float act_leaky_elu(float v) {
    float l = (v >= 0.0f) ? v : 0.01f * v;
    return (l > 0.0f) ? l : (__expf(l) - 1.0f);   // |err| ~1e-6 << 0.03 tol
}

// fragment fetch from pre-packed layout: pw[(c*128 + n)*4 + q] = 16B frag
__device__ __forceinline__ short8 ldfrag(const uint4* __restrict__ pw,
                                         int n, int c, int q) {
    union { uint4 u; short8 s; } r;
    r.u = pw[(size_t)(c * 128 + n) * 4 + q];
    return r.s;
}

__device__ __forceinline__ short8 load_afrag_f32(const float* __restrict__ p) {
    float4 a = ((const float4*)p)[0];
    float4 b = ((const float4*)p)[1];
    union { short8 s8; unsigned u[4]; } r;
    r.u[0] = f2bf_pack(a.x, a.y); r.u[1] = f2bf_pack(a.z, a.w);
    r.u[2] = f2bf_pack(b.x, b.y); r.u[3] = f2bf_pack(b.z, b.w);
    return r.s8;
}

// ---------------- weight prep: 5 x [128][128] fp32 -> bf16 frag layout --------
// pw[mat*2048 + (c*128 + n)*4 + q] = pairs of W[c*32+q*8+2j][n], j=0..3
__global__ __launch_bounds__(256)
void k_prep(const float* __restrict__ W0, const float* __restrict__ W1,
            const float* __restrict__ W2, const float* __restrict__ W3,
            const float* __restrict__ W4, uint4* __restrict__ pw) {
    const int mat = blockIdx.x;
    const float* W = (mat == 0) ? W0 : (mat == 1) ? W1 : (mat == 2) ? W2
                   : (mat == 3) ? W3 : W4;
    for (int f = threadIdx.x; f < 2048; f += 256) {
        int q = f & 3, n = (f >> 2) & 127, c = f >> 9;
        int k0 = c * 32 + q * 8;
        unsigned u[4];
        #pragma unroll
        for (int j = 0; j < 4; ++j)
            u[j] = f2bf_pack(W[(k0 + 2 * j) * 128 + n],
                             W[(k0 + 2 * j + 1) * 128 + n]);
        pw[(size_t)mat * 2048 + f] = make_uint4(u[0], u[1], u[2], u[3]);
    }
}

// ---------------- shared GEMM body: hb = bf16(x @ Wpre + bpre) ----------------
__device__ __forceinline__ void gemm_pre(const float* __restrict__ x,
                                         const uint4* __restrict__ pw,
                                         const float* __restrict__ bpre,
                                         unsigned short* __restrict__ hb,
                                         int N) {
    const int lane = threadIdx.x & 63;
    const int wv = threadIdx.x >> 6;
    const int q = lane >> 4;
    const int m = lane & 15;
    const int cg = wv * 32;
    short8 B[2][4];
    #pragma unroll
    for (int ct = 0; ct < 2; ++ct)
        #pragma unroll
        for (int c = 0; c < 4; ++c)
            B[ct][c] = ldfrag(pw, cg + ct * 16 + m, c, q);
    const float b0 = bpre[cg + m];
    const float b1 = bpre[cg + 16 + m];
    const int rb = blockIdx.x * 128;
    #pragma unroll 2
    for (int rt = 0; rt < 8; ++rt) {
        int row = rb + rt * 16 + m;
        int rc = min(row, N - 1);
        const float* xp = x + (size_t)rc * 128 + q * 8;
        float4v a0 = {0.f, 0.f, 0.f, 0.f}, a1 = {0.f, 0.f, 0.f, 0.f};
        #pragma unroll
        for (int c = 0; c < 4; ++c) {
            short8 a = load_afrag_f32(xp + c * 32);
            a0 = __builtin_amdgcn_mfma_f32_16x16x32_bf16(a, B[0][c], a0, 0, 0, 0);
            a1 = __builtin_amdgcn_mfma_f32_16x16x32_bf16(a, B[1][c], a1, 0, 0, 0);
        }
        #pragma unroll
        for (int r = 0; r < 4; ++r) {
            int ro = rb + rt * 16 + q * 4 + r;
            if (ro < N) {
                hb[(size_t)ro * 128 + cg + m]      = f2bf1(a0[r] + b0);
                hb[(size_t)ro * 128 + cg + 16 + m] = f2bf1(a1[r] + b1);
            }
        }
    }
}

// ---------------- fused GEMM + LDS-binned bucket count (packed path) ----------
__global__ __launch_bounds__(256)
void k_pre_bin1(const float* __restrict__ x, const uint4* __restrict__ pw,
                const float* __restrict__ bpre, unsigned short* __restrict__ hb,
                int N, int gd,
                const int* __restrict__ ei, int* __restrict__ gcnt,
                unsigned* __restrict__ aux, int* __restrict__ bbase,
                int E, int NBKT) {
    __shared__ int hist[1024];
    if ((int)blockIdx.x >= gd) {
        const int cb = (int)blockIdx.x - gd;
        const int tid = threadIdx.x;
        for (int j = tid; j < NBKT; j += 256) hist[j] = 0;
        __syncthreads();
        const int stride = NB_BIN * 256;
        for (int e = cb * 256 + tid; e < E; e += stride) {
            int col = ei[E + e];
            aux[e] = (unsigned)atomicAdd(&hist[col >> 7], 1);
        }
        __syncthreads();
        for (int j = tid; j < NBKT; j += 256) {
            int h = hist[j];
            int bb = (h > 0) ? atomicAdd(&gcnt[j], h) : 0;
            bbase[cb * 1024 + j] = bb;
        }
        return;
    }
    gemm_pre(x, pw, bpre, hb, N);
}

// ---------------- fused GEMM + device-atomic counting (fallback) --------------
__global__ __launch_bounds__(256)
void k_pre_cntD(const float* __restrict__ x, const uint4* __restrict__ pw,
                const float* __restrict__ bpre, unsigned short* __restrict__ hb,
                int N, int gd,
                const int* __restrict__ ei, int* __restrict__ cnti,
                int* __restrict__ rank, int E) {
    if ((int)blockIdx.x >= gd) {
        const int stride = ((int)gridDim.x - gd) * 256;
        for (int e = ((int)blockIdx.x - gd) * 256 + (int)threadIdx.x; e < E;
             e += stride) {
            rank[e] = atomicAdd(&cnti[ei[E + e]], 1);
        }
        return;
    }
    gemm_pre(x, pw, bpre, hb, N);
}

// ---------------- in-LDS exclusive scan over 1024 ints ------------------------
__device__ __forceinline__ void scan1024_excl(int* v, int* t) {
    const int tid = threadIdx.x;
    int a0 = v[tid * 4 + 0], a1 = v[tid * 4 + 1];
    int a2 = v[tid * 4 + 2], a3 = v[tid * 4 + 3];
    int ts = a0 + a1 + a2 + a3;
    t[tid] = ts;
    __syncthreads();
    #pragma unroll
    for (int off = 1; off < 256; off <<= 1) {
        int add = (tid >= off) ? t[tid - off] : 0;
        __syncthreads();
        t[tid] += add;
        __syncthreads();
    }
    int ex = t[tid] - ts;
    v[tid * 4 + 0] = ex;
    v[tid * 4 + 1] = ex + a0;
    v[tid * 4 + 2] = ex + a0 + a1;
    v[tid * 4 + 3] = ex + a0 + a1 + a2;
    __syncthreads();
}

// ---------------- scans (fallback path only) ----------------------------------
__global__ __launch_bounds__(256)
void k_scan1(const int* __restrict__ in, int* __restrict__ out,
             int* __restrict__ blksum, int n) {
    __shared__ int sh[256];
    const int tid = threadIdx.x;
    const int idx = blockIdx.x * 1024 + tid * 4;
    int v0 = (idx + 0 < n) ? in[idx + 0] : 0;
    int v1 = (idx + 1 < n) ? in[idx + 1] : 0;
    int v2 = (idx + 2 < n) ? in[idx + 2] : 0;
    int v3 = (idx + 3 < n) ? in[idx + 3] : 0;
    int tsum = v0 + v1 + v2 + v3;
    sh[tid] = tsum;
    __syncthreads();
    #pragma unroll
    for (int off = 1; off < 256; off <<= 1) {
        int add = (tid >= off) ? sh[tid - off] : 0;
        __syncthreads();
        sh[tid] += add;
        __syncthreads();
    }
    int excl = sh[tid] - tsum;
    if (idx + 0 < n) out[idx + 0] = excl;
    if (idx + 1 < n) out[idx + 1] = excl + v0;
    if (idx + 2 < n) out[idx + 2] = excl + v0 + v1;
    if (idx + 3 < n) out[idx + 3] = excl + v0 + v1 + v2;
    if (tid == 255) blksum[blockIdx.x] = sh[255];
}

__global__ __launch_bounds__(128)
void k_scan2(int* __restrict__ blksum, int nb) {
    __shared__ int sh[128];
    const int tid = threadIdx.x;
    int orig = (tid < nb) ? blksum[tid] : 0;
    sh[tid] = orig;
    __syncthreads();
    #pragma unroll
    for (int off = 1; off < 128; off <<= 1) {
        int add = (tid >= off) ? sh[tid - off] : 0;
        __syncthreads();
        sh[tid] += add;
        __syncthreads();
    }
    if (tid < nb) blksum[tid] = sh[tid] - orig;
}

// ---------------- bin scatter (scan folded in-LDS) ----------------------------
__global__ __launch_bounds__(256)
void k_bin2(const int* __restrict__ ei, const float* __restrict__ ew,
            const unsigned* __restrict__ aux, const int* __restrict__ gcnt,
            const int* __restrict__ bbase, uint2* __restrict__ binned,
            int E, int NBKT) {
    __shared__ int base[1024];
    __shared__ int tmp[256];
    const int cb = blockIdx.x;
    const int tid = threadIdx.x;
    #pragma unroll
    for (int k = 0; k < 4; ++k) {
        int i = tid * 4 + k;
        base[i] = (i < NBKT) ? gcnt[i] : 0;
    }
    __syncthreads();
    scan1024_excl(base, tmp);
    for (int j = tid; j < NBKT; j += 256) base[j] += bbase[cb * 1024 + j];
    __syncthreads();
    const int stride = NB_BIN * 256;
    for (int e = cb * 256 + tid; e < E; e += stride) {
        int col = ei[E + e];
        int src = ei[e];
        unsigned wq = (unsigned)__builtin_rintf(ew[e] * WQ_SCALE) & 0x7FFFu;
        int pos = base[col >> 7] + (int)aux[e];
        binned[pos] = make_uint2((wq << 17) | (unsigned)src, (unsigned)col);
    }
}

// ---------------- per-bucket CSR finalize (scan folded in-LDS) ----------------
__global__ __launch_bounds__(256)
void k_bktcsr(const uint2* __restrict__ binned, const int* __restrict__ gcnt,
              unsigned* __restrict__ recs, int* __restrict__ rowp,
              float* __restrict__ dis, int N, int E, int NBKT) {
    __shared__ int gb[1024];
    __shared__ int tmp[256];
    __shared__ int cnt[128];
    __shared__ int colbase[128];
    __shared__ unsigned long long wsum[128];
    const int bkt = blockIdx.x;
    const int tid = threadIdx.x;
    #pragma unroll
    for (int k = 0; k < 4; ++k) {
        int i = tid * 4 + k;
        gb[i] = (i < NBKT) ? gcnt[i] : 0;
    }
    if (tid < 128) { cnt[tid] = 0; wsum[tid] = 0ULL; }
    __syncthreads();
    scan1024_excl(gb, tmp);
    const int s = gb[bkt], e = gb[bkt + 1];
    for (int i = s + tid; i < e; i += 256) {
        uint2 r = binned[i];
        int cl = (int)(r.y & 127u);
        atomicAdd(&cnt[cl], 1);
        atomicAdd(&wsum[cl], (unsigned long long)(r.x >> 17));
    }
    __syncthreads();
    if (tid < 128) colbase[tid] = cnt[tid];
    __syncthreads();
    #pragma unroll
    for (int off = 1; off < 128; off <<= 1) {
        int add = 0;
        if (tid < 128 && tid >= off) add = colbase[tid - off];
        __syncthreads();
        if (tid < 128) colbase[tid] += add;
        __syncthreads();
    }
    if (tid < 128) {
        colbase[tid] = s + colbase[tid] - cnt[tid];   // absolute col base
        int node = bkt * 128 + tid;
        if (node < N) {
            rowp[node] = colbase[tid];
            float d = (float)wsum[tid] * WQ_INV;
            dis[node] = (wsum[tid] > 0ULL)
                          ? (1.0f / sqrtf(fmaxf(d, 1e-12f))) : 0.0f;
        }
        cnt[tid] = 0;
    }
    if (bkt == 0 && tid == 0) rowp[N] = E;
    __syncthreads();
    for (int i = s + tid; i < e; i += 256) {
        uint2 r = binned[i];
        int cl = (int)(r.y & 127u);
        int rk = atomicAdd(&cnt[cl], 1);
        recs[colbase[cl] + rk] = r.x;
    }
}

// ---------------- fallback scatter + degsum (wide recs) -----------------------
__global__ __launch_bounds__(256)
void k_scatterW(const int* __restrict__ ei, const float* __restrict__ ew,
                const int* __restrict__ rowp, const int* __restrict__ blks,
                const int* __restrict__ rank, int2* __restrict__ recs, int E) {
    int e = blockIdx.x * 256 + threadIdx.x;
    if (e < E) {
        int c = ei[E + e];
        int pos = rowp[c] + blks[c >> 10] + rank[e];
        recs[pos] = make_int2(ei[e], __float_as_int(ew[e]));
    }
}

__global__ __launch_bounds__(256)
void k_degsumW(const int* __restrict__ rowp, const int* __restrict__ blks,
               const int2* __restrict__ recs, float* __restrict__ dis, int N) {
    int n = blockIdx.x * 256 + threadIdx.x;
    if (n >= N) return;
    int s  = rowp[n] + blks[n >> 10];
    int eE = rowp[n + 1] + blks[(n + 1) >> 10];
    float d = 0.0f;
    for (int e = s; e < eE; ++e) d += __int_as_float(recs[e].y);
    dis[n] = (d > 0.0f) ? (1.0f / sqrtf(fmaxf(d, 1e-12f))) : 0.0f;
}

// ---------------- pull aggregation: quarter-wave rows, 4 edges/iter -----------
template <bool ABS>
__global__ __launch_bounds__(256)
void k_pull(const int* __restrict__ rowp, const int* __restrict__ blks,
            const void* __restrict__ recs_, const float* __restrict__ dis,
            const uint4* __restrict__ hb4, uint4* __restrict__ agb4,
            uint4* __restrict__ mnb4, int N) {
    const int node = blockIdx.x * 4 + (threadIdx.x >> 6);
    if (node >= N) return;
    const int lane = threadIdx.x & 63;
    const int q4 = lane >> 4;
    const int sub = lane & 15;
    int s, eE;
    if (ABS) {
        s  = __builtin_amdgcn_readfirstlane(rowp[node]);
        eE = __builtin_amdgcn_readfirstlane(rowp[node + 1]);
    } else {
        s  = __builtin_amdgcn_readfirstlane(rowp[node] + blks[node >> 10]);
        eE = __builtin_amdgcn_readfirstlane(rowp[node + 1] +
                                            blks[(node + 1) >> 10]);
    }
    const float dcol = dis[node];
    const float im = 1.0f / fmaxf((float)(eE - s), 1.0f);

    float aA[8], aM[8];
    #pragma unroll
    for (int i = 0; i < 8; ++i) { aA[i] = 0.f; aM[i] = 0.f; }

    #pragma unroll 2
    for (int e = s; e < eE; e += 4) {
        int el = e + q4;
        bool ok = el < eE;
        int el2 = ok ? el : (eE - 1);
        int src; float w;
        if (ABS) {
            unsigned rv = ((const unsigned*)recs_)[el2];
            src = (int)(rv & 0x1FFFFu);
            w = (float)(rv >> 17) * WQ_INV;
        } else {
            int2 rv = ((const int2*)recs_)[el2];
            src = rv.x;
            w = __int_as_float(rv.y);
        }
        if (!ok) w = 0.f;
        float c = dis[src] * w;
        uint4 u = hb4[(size_t)src * 16 + sub];
        float f0 = __uint_as_float(u.x << 16);
        float f1 = __uint_as_float(u.x & 0xFFFF0000u);
        float f2 = __uint_as_float(u.y << 16);
        float f3 = __uint_as_float(u.y & 0xFFFF0000u);
        float f4 = __uint_as_float(u.z << 16);
        float f5 = __uint_as_float(u.z & 0xFFFF0000u);
        float f6 = __uint_as_float(u.w << 16);
        float f7 = __uint_as_float(u.w & 0xFFFF0000u);
        aA[0] = fmaf(c, f0, aA[0]); aM[0] = fmaf(w, f0, aM[0]);
        aA[1] = fmaf(c, f1, aA[1]); aM[1] = fmaf(w, f1, aM[1]);
        aA[2] = fmaf(c, f2, aA[2]); aM[2] = fmaf(w, f2, aM[2]);
        aA[3] = fmaf(c, f3, aA[3]); aM[3] = fmaf(w, f3, aM[3]);
        aA[4] = fmaf(c, f4, aA[4]); aM[4] = fmaf(w, f4, aM[4]);
        aA[5] = fmaf(c, f5, aA[5]); aM[5] = fmaf(w, f5, aM[5]);
        aA[6] = fmaf(c, f6, aA[6]); aM[6] = fmaf(w, f6, aM[6]);
        aA[7] = fmaf(c, f7, aA[7]); aM[7] = fmaf(w, f7, aM[7]);
    }

    #pragma unroll
    for (int i = 0; i < 8; ++i) {
        aA[i] += __shfl_xor(aA[i], 32, 64);
        aA[i] += __shfl_xor(aA[i], 16, 64);
        aM[i] += __shfl_xor(aM[i], 32, 64);
        aM[i] += __shfl_xor(aM[i], 16, 64);
    }

    if (q4 == 0) {
        uint4 o;
        o.x = f2bf_pack(aA[0] * dcol, aA[1] * dcol);
        o.y = f2bf_pack(aA[2] * dcol, aA[3] * dcol);
        o.z = f2bf_pack(aA[4] * dcol, aA[5] * dcol);
        o.w = f2bf_pack(aA[6] * dcol, aA[7] * dcol);
        agb4[(size_t)node * 16 + sub] = o;
    } else if (q4 == 1) {
        uint4 o;
        o.x = f2bf_pack(aM[0] * im, aM[1] * im);
        o.y = f2bf_pack(aM[2] * im, aM[3] * im);
        o.z = f2bf_pack(aM[4] * im, aM[5] * im);
        o.w = f2bf_pack(aM[6] * im, aM[7] * im);
        mnb4[(size_t)node * 16 + sub] = o;
    }
}

// ---------------- fused epilogue: 64 rows/block, 4 indep MFMA chains ----------
// 512 threads: waves 0-3 ARMA (relu), waves 4-7 SAGE (leaky+elu).
__global__ __launch_bounds__(512)
void k_final2(const unsigned short* __restrict__ agb,
              const unsigned short* __restrict__ mnb,
              const unsigned short* __restrict__ hb,
              const uint4* __restrict__ pw,
              const float* __restrict__ ab, const float* __restrict__ bsl,
              float* __restrict__ out, int N) {
    const int lane = threadIdx.x & 63;
    const int wv = threadIdx.x >> 6;           // 0..7
    const bool sg = wv >= 4;
    const int q = lane >> 4;
    const int m = lane & 15;
    const int cg = (wv & 3) * 32;
    const unsigned short* A1 = sg ? mnb : agb;
    const uint4* W1 = pw + (size_t)(sg ? 3 : 1) * 2048;
    const uint4* W2 = pw + (size_t)(sg ? 4 : 2) * 2048;
    const float* bias = sg ? bsl : ab;
    float* op = out + (sg ? 128 : 0);
    short8 B1[2][4], B2[2][4];
    #pragma unroll
    for (int ct = 0; ct < 2; ++ct)
        #pragma unroll
        for (int c = 0; c < 4; ++c) {
            B1[ct][c] = ldfrag(W1, cg + ct * 16 + m, c, q);
            B2[ct][c] = ldfrag(W2, cg + ct * 16 + m, c, q);
        }
    const float b0 = bias[cg + m];
    const float b1 = bias[cg + 16 + m];
    const int rb = blockIdx.x * 64;
    #pragma unroll 2
    for (int rt = 0; rt < 4; ++rt) {
        int row = rb + rt * 16 + m;
        int rc = min(row, N - 1);
        const short8* a1 = (const short8*)(A1 + (size_t)rc * 128 + q * 8);
        const short8* a2 = (const short8*)(hb + (size_t)rc * 128 + q * 8);
        float4v c0a = {0.f,0.f,0.f,0.f}, c0b = {0.f,0.f,0.f,0.f};
        float4v c1a = {0.f,0.f,0.f,0.f}, c1b = {0.f,0.f,0.f,0.f};
        #pragma unroll
        for (int c = 0; c < 4; ++c) {
            short8 a = a1[c * 4];
            short8 b = a2[c * 4];
            c0a = __builtin_amdgcn_mfma_f32_16x16x32_bf16(a, B1[0][c], c0a, 0, 0, 0);
            c1a = __builtin_amdgcn_mfma_f32_16x16x32_bf16(a, B1[1][c], c1a, 0, 0, 0);
            c0b = __builtin_amdgcn_mfma_f32_16x16x32_bf16(b, B2[0][c], c0b, 0, 0, 0);
            c1b = __builtin_amdgcn_mfma_f32_16x16x32_bf16(b, B2[1][c], c1b, 0, 0, 0);
        }
        #pragma unroll
        for (int r = 0; r < 4; ++r) {
            int ro = rb + rt * 16 + q * 4 + r;
            if (ro < N) {
                float v0 = c0a[r] + c0b[r] + b0;
                float v1 = c1a[r] + c1b[r] + b1;
                if (!sg) { v0 = fmaxf(v0, 0.f); v1 = fmaxf(v1, 0.f); }
                else     { v0 = act_leaky_elu(v0); v1 = act_leaky_elu(v1); }
                op[(size_t)ro * 256 + cg + m]      = v0;
                op[(size_t)ro * 256 + cg + 16 + m] = v1;
            }
        }
    }
}

extern "C" void kernel_launch(void* const* d_in, const int* in_sizes, int n_in,
                              void* d_out, int out_size, void* d_ws, size_t ws_size,
                              hipStream_t stream) {
    const float* x    = (const float*)d_in[0];
    const int*   ei   = (const int*)d_in[1];
    const float* ew   = (const float*)d_in[2];
    const float* Wpre = (const float*)d_in[3];
    const float* bpre = (const float*)d_in[4];
    const float* Wai  = (const float*)d_in[5];
    const float* War  = (const float*)d_in[6];
    const float* ab   = (const float*)d_in[7];
    const float* Wsl  = (const float*)d_in[8];
    const float* bsl  = (const float*)d_in[9];
    const float* Wsr  = (const float*)d_in[10];

    const int N = in_sizes[0] / 128;
    const int E = in_sizes[2];
    const size_t NF = (size_t)N * 128;
    const int NBKT = (N + 127) >> 7;
    const bool packed = (N <= 130944);   // NBKT+1 <= 1024 and src fits 17 bits

    char* p = (char*)d_ws;
    auto take = [&p](size_t bytes) {
        char* r = p;
        p += (bytes + 255) & ~(size_t)255;
        return r;
    };
    unsigned short* hb  = (unsigned short*)take(NF * 2);
    unsigned short* agb = (unsigned short*)take(NF * 2);
    unsigned short* mnb = (unsigned short*)take(NF * 2);
    unsigned* recs = (unsigned*)take(packed ? (size_t)E * 4 : (size_t)E * 8);
    int*   rowp = (int*)take((size_t)(N + 1) * 4);
    float* dis  = (float*)take((size_t)N * 4);
    int*   cti  = (int*)take((size_t)(N + 1) * 4);   // fallback count
    int*   blks = (int*)take(128 * 4);
    int*   gcnt = (int*)take(1025 * 4);
    uint4* pw   = (uint4*)take((size_t)5 * 2048 * 16);

    // overlays (packed path): binned on agb; aux+bbase on mnb.
    size_t binB = (size_t)E * 8;
    uint2* binned = (NF * 2 >= binB) ? (uint2*)agb : (uint2*)take(binB);
    size_t auxB = ((size_t)E * 4 + 255) & ~(size_t)255;
    size_t bbB  = (size_t)NB_BIN * 1024 * 4;
    unsigned* aux; int* bbase;
    if (NF * 2 >= auxB + bbB) {
        aux = (unsigned*)mnb;
        bbase = (int*)((char*)mnb + auxB);
    } else {
        aux = (unsigned*)take((size_t)E * 4);
        bbase = (int*)take(bbB);
    }

    const int gd = (N + 127) / 128;
    const int gf = (N + 63) / 64;
    const int ge = (E + 255) / 256;
    const int gv = (N + 255) / 256;
    const int ns = N + 1;
    const int nb = (ns + 1023) / 1024;

    k_prep<<<5, 256, 0, stream>>>(Wpre, Wai, War, Wsl, Wsr, pw);

    if (packed) {
        hipMemsetAsync(gcnt, 0, (size_t)(NBKT + 1) * 4, stream);
        k_pre_bin1<<<gd + NB_BIN, 256, 0, stream>>>(x, pw, bpre, hb, N, gd,
                                                    ei, gcnt, aux, bbase,
                                                    E, NBKT);
        k_bin2<<<NB_BIN, 256, 0, stream>>>(ei, ew, aux, gcnt, bbase,
                                           binned, E, NBKT);
        k_bktcsr<<<NBKT, 256, 0, stream>>>(binned, gcnt, recs, rowp, dis,
                                           N, E, NBKT);
        k_pull<true><<<(N + 3) / 4, 256, 0, stream>>>(rowp, blks, recs, dis,
            (const uint4*)hb, (uint4*)agb, (uint4*)mnb, N);
    } else {
        hipMemsetAsync(cti, 0, (size_t)(N + 1) * 4, stream);
        k_pre_cntD<<<gd + 2048, 256, 0, stream>>>(x, pw, bpre, hb, N, gd,
                                                  ei, cti, (int*)aux, E);
        k_scan1<<<nb, 256, 0, stream>>>(cti, rowp, blks, ns);
        k_scan2<<<1, 128, 0, stream>>>(blks, nb);
        k_scatterW<<<ge, 256, 0, stream>>>(ei, ew, rowp, blks, (int*)aux,
                                           (int2*)recs, E);
        k_degsumW<<<gv, 256, 0, stream>>>(rowp, blks, (const int2*)recs,
                                          dis, N);
        k_pull<false><<<(N + 3) / 4, 256, 0, stream>>>(rowp, blks, recs, dis,
            (const uint4*)hb, (uint4*)agb, (uint4*)mnb, N);
    }

    k_final2<<<gf, 512, 0, stream>>>(agb, mnb, hb, pw, ab, bsl,
                                     (float*)d_out, N);
}

// Round 7
// 338.478 us; speedup vs baseline: 1.2787x; 1.1028x over previous
//
#include <hip/hip_runtime.h>
#include <math.h>

// ---------------------------------------------------------------------------
// N=100000, E=1600000, dims 128. Round 13:
//  JOURNAL: r10 refuted XCD-local atomics; r11 LDS-binned sort (425->383);
//  r12 prepacked W + 4 MFMA chains (k_final2 86->74.5, VALU 23->13%).
//  k_final2 is still latency-bound (Mfma 6.5 / VALU 13 / HBM 24 / Occ 31:
//  ~80% waits on 16B x 256B-stride A-fragment gathers).
//  This round: k_final2 stages the block's 64-row agb/mnb/hb tiles in LDS
//  (3 x 17 KB, 272-B padded stride -> <=2-way banks = free per m136),
//  coalesced uint4 staging, W-frags load while staging flies, ONE barrier;
//  fragment reads become ds_read_b128. hb fetched once/block (was twice).
//  Everything else byte-identical to r12.
// ---------------------------------------------------------------------------

typedef __attribute__((ext_vector_type(8))) short short8;   // 8 bf16 (4 VGPR)
typedef __attribute__((ext_vector_type(4))) float float4v;  // 4 fp32 acc

#define WQ_SCALE 32767.0f
#define WQ_INV   (1.0f / 32767.0f)
#define NB_BIN   256   // counting/scatter blocks (must match kBin1<->kBin2)
#define TSTRIDE  272   // LDS tile row stride in bytes (256 + 16 pad)

__device__ __forceinline__ unsigned f2bf_pack(float a, float b) {
    unsigned ua = __float_as_uint(a);
    unsigned ub = __float_as_uint(b);
    ua += 0x7FFF + ((ua >> 16) & 1);   // RNE
    ub += 0x7FFF + ((ub >> 16) & 1);
    return (ua >> 16) | (ub & 0xFFFF0000u);
}

__device__ __forceinline__ unsigned short f2bf1(float a) {
    unsigned u = __float_as_uint(a);
    u += 0x7FFF + ((u >> 16) & 1);
    return (unsigned short)(u >> 16);
}

__device__ __forceinline__ float act_leaky_elu(float v) {
    float l = (v >= 0.0f) ? v : 0.01f * v;
    return (l > 0.0f) ? l : (__expf(l) - 1.0f);   // |err| ~1e-6 << 0.03 tol
}

// fragment fetch from pre-packed layout: pw[(c*128 + n)*4 + q] = 16B frag
__device__ __forceinline__ short8 ldfrag(const uint4* __restrict__ pw,
                                         int n, int c, int q) {
    union { uint4 u; short8 s; } r;
    r.u = pw[(size_t)(c * 128 + n) * 4 + q];
    return r.s;
}

__device__ __forceinline__ short8 load_afrag_f32(const float* __restrict__ p) {
    float4 a = ((const float4*)p)[0];
    float4 b = ((const float4*)p)[1];
    union { short8 s8; unsigned u[4]; } r;
    r.u[0] = f2bf_pack(a.x, a.y); r.u[1] = f2bf_pack(a.z, a.w);
    r.u[2] = f2bf_pack(b.x, b.y); r.u[3] = f2bf_pack(b.z, b.w);
    return r.s8;
}

// ---------------- weight prep: 5 x [128][128] fp32 -> bf16 frag layout --------
// pw[mat*2048 + (c*128 + n)*4 + q] = pairs of W[c*32+q*8+2j][n], j=0..3
__global__ __launch_bounds__(256)
void k_prep(const float* __restrict__ W0, const float* __restrict__ W1,
            const float* __restrict__ W2, const float* __restrict__ W3,
            const float* __restrict__ W4, uint4* __restrict__ pw) {
    const int mat = blockIdx.x;
    const float* W = (mat == 0) ? W0 : (mat == 1) ? W1 : (mat == 2) ? W2
                   : (mat == 3) ? W3 : W4;
    for (int f = threadIdx.x; f < 2048; f += 256) {
        int q = f & 3, n = (f >> 2) & 127, c = f >> 9;
        int k0 = c * 32 + q * 8;
        unsigned u[4];
        #pragma unroll
        for (int j = 0; j < 4; ++j)
            u[j] = f2bf_pack(W[(k0 + 2 * j) * 128 + n],
                             W[(k0 + 2 * j + 1) * 128 + n]);
        pw[(size_t)mat * 2048 + f] = make_uint4(u[0], u[1], u[2], u[3]);
    }
}

// ---------------- shared GEMM body: hb = bf16(x @ Wpre + bpre) ----------------
__device__ __forceinline__ void gemm_pre(const float* __restrict__ x,
                                         const uint4* __restrict__ pw,
                                         const float* __restrict__ bpre,
                                         unsigned short* __restrict__ hb,
                                         int N) {
    const int lane = threadIdx.x & 63;
    const int wv = threadIdx.x >> 6;
    const int q = lane >> 4;
    const int m = lane & 15;
    const int cg = wv * 32;
    short8 B[2][4];
    #pragma unroll
    for (int ct = 0; ct < 2; ++ct)
        #pragma unroll
        for (int c = 0; c < 4; ++c)
            B[ct][c] = ldfrag(pw, cg + ct * 16 + m, c, q);
    const float b0 = bpre[cg + m];
    const float b1 = bpre[cg + 16 + m];
    const int rb = blockIdx.x * 128;
    #pragma unroll 2
    for (int rt = 0; rt < 8; ++rt) {
        int row = rb + rt * 16 + m;
        int rc = min(row, N - 1);
        const float* xp = x + (size_t)rc * 128 + q * 8;
        float4v a0 = {0.f, 0.f, 0.f, 0.f}, a1 = {0.f, 0.f, 0.f, 0.f};
        #pragma unroll
        for (int c = 0; c < 4; ++c) {
            short8 a = load_afrag_f32(xp + c * 32);
            a0 = __builtin_amdgcn_mfma_f32_16x16x32_bf16(a, B[0][c], a0, 0, 0, 0);
            a1 = __builtin_amdgcn_mfma_f32_16x16x32_bf16(a, B[1][c], a1, 0, 0, 0);
        }
        #pragma unroll
        for (int r = 0; r < 4; ++r) {
            int ro = rb + rt * 16 + q * 4 + r;
            if (ro < N) {
                hb[(size_t)ro * 128 + cg + m]      = f2bf1(a0[r] + b0);
                hb[(size_t)ro * 128 + cg + 16 + m] = f2bf1(a1[r] + b1);
            }
        }
    }
}

// ---------------- fused GEMM + LDS-binned bucket count (packed path) ----------
__global__ __launch_bounds__(256)
void k_pre_bin1(const float* __restrict__ x, const uint4* __restrict__ pw,
                const float* __restrict__ bpre, unsigned short* __restrict__ hb,
                int N, int gd,
                const int* __restrict__ ei, int* __restrict__ gcnt,
                unsigned* __restrict__ aux, int* __restrict__ bbase,
                int E, int NBKT) {
    __shared__ int hist[1024];
    if ((int)blockIdx.x >= gd) {
        const int cb = (int)blockIdx.x - gd;
        const int tid = threadIdx.x;
        for (int j = tid; j < NBKT; j += 256) hist[j] = 0;
        __syncthreads();
        const int stride = NB_BIN * 256;
        for (int e = cb * 256 + tid; e < E; e += stride) {
            int col = ei[E + e];
            aux[e] = (unsigned)atomicAdd(&hist[col >> 7], 1);
        }
        __syncthreads();
        for (int j = tid; j < NBKT; j += 256) {
            int h = hist[j];
            int bb = (h > 0) ? atomicAdd(&gcnt[j], h) : 0;
            bbase[cb * 1024 + j] = bb;
        }
        return;
    }
    gemm_pre(x, pw, bpre, hb, N);
}

// ---------------- fused GEMM + device-atomic counting (fallback) --------------
__global__ __launch_bounds__(256)
void k_pre_cntD(const float* __restrict__ x, const uint4* __restrict__ pw,
                const float* __restrict__ bpre, unsigned short* __restrict__ hb,
                int N, int gd,
                const int* __restrict__ ei, int* __restrict__ cnti,
                int* __restrict__ rank, int E) {
    if ((int)blockIdx.x >= gd) {
        const int stride = ((int)gridDim.x - gd) * 256;
        for (int e = ((int)blockIdx.x - gd) * 256 + (int)threadIdx.x; e < E;
             e += stride) {
            rank[e] = atomicAdd(&cnti[ei[E + e]], 1);
        }
        return;
    }
    gemm_pre(x, pw, bpre, hb, N);
}

// ---------------- in-LDS exclusive scan over 1024 ints ------------------------
__device__ __forceinline__ void scan1024_excl(int* v, int* t) {
    const int tid = threadIdx.x;
    int a0 = v[tid * 4 + 0], a1 = v[tid * 4 + 1];
    int a2 = v[tid * 4 + 2], a3 = v[tid * 4 + 3];
    int ts = a0 + a1 + a2 + a3;
    t[tid] = ts;
    __syncthreads();
    #pragma unroll
    for (int off = 1; off < 256; off <<= 1) {
        int add = (tid >= off) ? t[tid - off] : 0;
        __syncthreads();
        t[tid] += add;
        __syncthreads();
    }
    int ex = t[tid] - ts;
    v[tid * 4 + 0] = ex;
    v[tid * 4 + 1] = ex + a0;
    v[tid * 4 + 2] = ex + a0 + a1;
    v[tid * 4 + 3] = ex + a0 + a1 + a2;
    __syncthreads();
}

// ---------------- scans (fallback path only) ----------------------------------
__global__ __launch_bounds__(256)
void k_scan1(const int* __restrict__ in, int* __restrict__ out,
             int* __restrict__ blksum, int n) {
    __shared__ int sh[256];
    const int tid = threadIdx.x;
    const int idx = blockIdx.x * 1024 + tid * 4;
    int v0 = (idx + 0 < n) ? in[idx + 0] : 0;
    int v1 = (idx + 1 < n) ? in[idx + 1] : 0;
    int v2 = (idx + 2 < n) ? in[idx + 2] : 0;
    int v3 = (idx + 3 < n) ? in[idx + 3] : 0;
    int tsum = v0 + v1 + v2 + v3;
    sh[tid] = tsum;
    __syncthreads();
    #pragma unroll
    for (int off = 1; off < 256; off <<= 1) {
        int add = (tid >= off) ? sh[tid - off] : 0;
        __syncthreads();
        sh[tid] += add;
        __syncthreads();
    }
    int excl = sh[tid] - tsum;
    if (idx + 0 < n) out[idx + 0] = excl;
    if (idx + 1 < n) out[idx + 1] = excl + v0;
    if (idx + 2 < n) out[idx + 2] = excl + v0 + v1;
    if (idx + 3 < n) out[idx + 3] = excl + v0 + v1 + v2;
    if (tid == 255) blksum[blockIdx.x] = sh[255];
}

__global__ __launch_bounds__(128)
void k_scan2(int* __restrict__ blksum, int nb) {
    __shared__ int sh[128];
    const int tid = threadIdx.x;
    int orig = (tid < nb) ? blksum[tid] : 0;
    sh[tid] = orig;
    __syncthreads();
    #pragma unroll
    for (int off = 1; off < 128; off <<= 1) {
        int add = (tid >= off) ? sh[tid - off] : 0;
        __syncthreads();
        sh[tid] += add;
        __syncthreads();
    }
    if (tid < nb) blksum[tid] = sh[tid] - orig;
}

// ---------------- bin scatter (scan folded in-LDS) ----------------------------
__global__ __launch_bounds__(256)
void k_bin2(const int* __restrict__ ei, const float* __restrict__ ew,
            const unsigned* __restrict__ aux, const int* __restrict__ gcnt,
            const int* __restrict__ bbase, uint2* __restrict__ binned,
            int E, int NBKT) {
    __shared__ int base[1024];
    __shared__ int tmp[256];
    const int cb = blockIdx.x;
    const int tid = threadIdx.x;
    #pragma unroll
    for (int k = 0; k < 4; ++k) {
        int i = tid * 4 + k;
        base[i] = (i < NBKT) ? gcnt[i] : 0;
    }
    __syncthreads();
    scan1024_excl(base, tmp);
    for (int j = tid; j < NBKT; j += 256) base[j] += bbase[cb * 1024 + j];
    __syncthreads();
    const int stride = NB_BIN * 256;
    for (int e = cb * 256 + tid; e < E; e += stride) {
        int col = ei[E + e];
        int src = ei[e];
        unsigned wq = (unsigned)__builtin_rintf(ew[e] * WQ_SCALE) & 0x7FFFu;
        int pos = base[col >> 7] + (int)aux[e];
        binned[pos] = make_uint2((wq << 17) | (unsigned)src, (unsigned)col);
    }
}

// ---------------- per-bucket CSR finalize (scan folded in-LDS) ----------------
__global__ __launch_bounds__(256)
void k_bktcsr(const uint2* __restrict__ binned, const int* __restrict__ gcnt,
              unsigned* __restrict__ recs, int* __restrict__ rowp,
              float* __restrict__ dis, int N, int E, int NBKT) {
    __shared__ int gb[1024];
    __shared__ int tmp[256];
    __shared__ int cnt[128];
    __shared__ int colbase[128];
    __shared__ unsigned long long wsum[128];
    const int bkt = blockIdx.x;
    const int tid = threadIdx.x;
    #pragma unroll
    for (int k = 0; k < 4; ++k) {
        int i = tid * 4 + k;
        gb[i] = (i < NBKT) ? gcnt[i] : 0;
    }
    if (tid < 128) { cnt[tid] = 0; wsum[tid] = 0ULL; }
    __syncthreads();
    scan1024_excl(gb, tmp);
    const int s = gb[bkt], e = gb[bkt + 1];
    for (int i = s + tid; i < e; i += 256) {
        uint2 r = binned[i];
        int cl = (int)(r.y & 127u);
        atomicAdd(&cnt[cl], 1);
        atomicAdd(&wsum[cl], (unsigned long long)(r.x >> 17));
    }
    __syncthreads();
    if (tid < 128) colbase[tid] = cnt[tid];
    __syncthreads();
    #pragma unroll
    for (int off = 1; off < 128; off <<= 1) {
        int add = 0;
        if (tid < 128 && tid >= off) add = colbase[tid - off];
        __syncthreads();
        if (tid < 128) colbase[tid] += add;
        __syncthreads();
    }
    if (tid < 128) {
        colbase[tid] = s + colbase[tid] - cnt[tid];   // absolute col base
        int node = bkt * 128 + tid;
        if (node < N) {
            rowp[node] = colbase[tid];
            float d = (float)wsum[tid] * WQ_INV;
            dis[node] = (wsum[tid] > 0ULL)
                          ? (1.0f / sqrtf(fmaxf(d, 1e-12f))) : 0.0f;
        }
        cnt[tid] = 0;
    }
    if (bkt == 0 && tid == 0) rowp[N] = E;
    __syncthreads();
    for (int i = s + tid; i < e; i += 256) {
        uint2 r = binned[i];
        int cl = (int)(r.y & 127u);
        int rk = atomicAdd(&cnt[cl], 1);
        recs[colbase[cl] + rk] = r.x;
    }
}

// ---------------- fallback scatter + degsum (wide recs) -----------------------
__global__ __launch_bounds__(256)
void k_scatterW(const int* __restrict__ ei, const float* __restrict__ ew,
                const int* __restrict__ rowp, const int* __restrict__ blks,
                const int* __restrict__ rank, int2* __restrict__ recs, int E) {
    int e = blockIdx.x * 256 + threadIdx.x;
    if (e < E) {
        int c = ei[E + e];
        int pos = rowp[c] + blks[c >> 10] + rank[e];
        recs[pos] = make_int2(ei[e], __float_as_int(ew[e]));
    }
}

__global__ __launch_bounds__(256)
void k_degsumW(const int* __restrict__ rowp, const int* __restrict__ blks,
               const int2* __restrict__ recs, float* __restrict__ dis, int N) {
    int n = blockIdx.x * 256 + threadIdx.x;
    if (n >= N) return;
    int s  = rowp[n] + blks[n >> 10];
    int eE = rowp[n + 1] + blks[(n + 1) >> 10];
    float d = 0.0f;
    for (int e = s; e < eE; ++e) d += __int_as_float(recs[e].y);
    dis[n] = (d > 0.0f) ? (1.0f / sqrtf(fmaxf(d, 1e-12f))) : 0.0f;
}

// ---------------- pull aggregation: quarter-wave rows, 4 edges/iter -----------
template <bool ABS>
__global__ __launch_bounds__(256)
void k_pull(const int* __restrict__ rowp, const int* __restrict__ blks,
            const void* __restrict__ recs_, const float* __restrict__ dis,
            const uint4* __restrict__ hb4, uint4* __restrict__ agb4,
            uint4* __restrict__ mnb4, int N) {
    const int node = blockIdx.x * 4 + (threadIdx.x >> 6);
    if (node >= N) return;
    const int lane = threadIdx.x & 63;
    const int q4 = lane >> 4;
    const int sub = lane & 15;
    int s, eE;
    if (ABS) {
        s  = __builtin_amdgcn_readfirstlane(rowp[node]);
        eE = __builtin_amdgcn_readfirstlane(rowp[node + 1]);
    } else {
        s  = __builtin_amdgcn_readfirstlane(rowp[node] + blks[node >> 10]);
        eE = __builtin_amdgcn_readfirstlane(rowp[node + 1] +
                                            blks[(node + 1) >> 10]);
    }
    const float dcol = dis[node];
    const float im = 1.0f / fmaxf((float)(eE - s), 1.0f);

    float aA[8], aM[8];
    #pragma unroll
    for (int i = 0; i < 8; ++i) { aA[i] = 0.f; aM[i] = 0.f; }

    #pragma unroll 2
    for (int e = s; e < eE; e += 4) {
        int el = e + q4;
        bool ok = el < eE;
        int el2 = ok ? el : (eE - 1);
        int src; float w;
        if (ABS) {
            unsigned rv = ((const unsigned*)recs_)[el2];
            src = (int)(rv & 0x1FFFFu);
            w = (float)(rv >> 17) * WQ_INV;
        } else {
            int2 rv = ((const int2*)recs_)[el2];
            src = rv.x;
            w = __int_as_float(rv.y);
        }
        if (!ok) w = 0.f;
        float c = dis[src] * w;
        uint4 u = hb4[(size_t)src * 16 + sub];
        float f0 = __uint_as_float(u.x << 16);
        float f1 = __uint_as_float(u.x & 0xFFFF0000u);
        float f2 = __uint_as_float(u.y << 16);
        float f3 = __uint_as_float(u.y & 0xFFFF0000u);
        float f4 = __uint_as_float(u.z << 16);
        float f5 = __uint_as_float(u.z & 0xFFFF0000u);
        float f6 = __uint_as_float(u.w << 16);
        float f7 = __uint_as_float(u.w & 0xFFFF0000u);
        aA[0] = fmaf(c, f0, aA[0]); aM[0] = fmaf(w, f0, aM[0]);
        aA[1] = fmaf(c, f1, aA[1]); aM[1] = fmaf(w, f1, aM[1]);
        aA[2] = fmaf(c, f2, aA[2]); aM[2] = fmaf(w, f2, aM[2]);
        aA[3] = fmaf(c, f3, aA[3]); aM[3] = fmaf(w, f3, aM[3]);
        aA[4] = fmaf(c, f4, aA[4]); aM[4] = fmaf(w, f4, aM[4]);
        aA[5] = fmaf(c, f5, aA[5]); aM[5] = fmaf(w, f5, aM[5]);
        aA[6] = fmaf(c, f6, aA[6]); aM[6] = fmaf(w, f6, aM[6]);
        aA[7] = fmaf(c, f7, aA[7]); aM[7] = fmaf(w, f7, aM[7]);
    }

    #pragma unroll
    for (int i = 0; i < 8; ++i) {
        aA[i] += __shfl_xor(aA[i], 32, 64);
        aA[i] += __shfl_xor(aA[i], 16, 64);
        aM[i] += __shfl_xor(aM[i], 32, 64);
        aM[i] += __shfl_xor(aM[i], 16, 64);
    }

    if (q4 == 0) {
        uint4 o;
        o.x = f2bf_pack(aA[0] * dcol, aA[1] * dcol);
        o.y = f2bf_pack(aA[2] * dcol, aA[3] * dcol);
        o.z = f2bf_pack(aA[4] * dcol, aA[5] * dcol);
        o.w = f2bf_pack(aA[6] * dcol, aA[7] * dcol);
        agb4[(size_t)node * 16 + sub] = o;
    } else if (q4 == 1) {
        uint4 o;
        o.x = f2bf_pack(aM[0] * im, aM[1] * im);
        o.y = f2bf_pack(aM[2] * im, aM[3] * im);
        o.z = f2bf_pack(aM[4] * im, aM[5] * im);
        o.w = f2bf_pack(aM[6] * im, aM[7] * im);
        mnb4[(size_t)node * 16 + sub] = o;
    }
}

// ---------------- fused epilogue: LDS-staged A-tiles, 4 indep MFMA chains -----
// 512 threads, 64 rows/block: stage agb/mnb/hb 64x256B tiles in LDS (272-B
// padded stride, <=2-way banks), W-frags load under staging, ONE barrier.
// Waves 0-3 ARMA (relu), waves 4-7 SAGE (leaky+elu).
__global__ __launch_bounds__(512)
void k_final2(const unsigned short* __restrict__ agb,
              const unsigned short* __restrict__ mnb,
              const unsigned short* __restrict__ hb,
              const uint4* __restrict__ pw,
              const float* __restrict__ ab, const float* __restrict__ bsl,
              float* __restrict__ out, int N) {
    __shared__ char lds[3 * 64 * TSTRIDE];          // 52224 B
    const int tid = threadIdx.x;
    const int lane = tid & 63;
    const int wv = tid >> 6;                        // 0..7
    const bool sg = wv >= 4;
    const int q = lane >> 4;
    const int m = lane & 15;
    const int cg = (wv & 3) * 32;
    const int rb = blockIdx.x * 64;

    // issue staging loads first (coalesced: consecutive tid -> consecutive 16B)
    uint4 stg[3][2];
    {
        const uint4* s0 = (const uint4*)agb;
        const uint4* s1 = (const uint4*)mnb;
        const uint4* s2 = (const uint4*)hb;
        #pragma unroll
        for (int h = 0; h < 2; ++h) {
            int i = tid + h * 512;
            int row = i >> 4, ch = i & 15;
            size_t g = (size_t)min(rb + row, N - 1) * 16 + ch;
            stg[0][h] = s0[g];
            stg[1][h] = s1[g];
            stg[2][h] = s2[g];
        }
    }

    // W fragments + bias while staging loads are in flight (L2-hot)
    const uint4* W1 = pw + (size_t)(sg ? 3 : 1) * 2048;
    const uint4* W2 = pw + (size_t)(sg ? 4 : 2) * 2048;
    const float* bias = sg ? bsl : ab;
    short8 B1[2][4], B2[2][4];
    #pragma unroll
    for (int ct = 0; ct < 2; ++ct)
        #pragma unroll
        for (int c = 0; c < 4; ++c) {
            B1[ct][c] = ldfrag(W1, cg + ct * 16 + m, c, q);
            B2[ct][c] = ldfrag(W2, cg + ct * 16 + m, c, q);
        }
    const float b0 = bias[cg + m];
    const float b1 = bias[cg + 16 + m];

    // LDS writes + barrier
    #pragma unroll
    for (int t = 0; t < 3; ++t)
        #pragma unroll
        for (int h = 0; h < 2; ++h) {
            int i = tid + h * 512;
            int row = i >> 4, ch = i & 15;
            *(uint4*)&lds[t * 64 * TSTRIDE + row * TSTRIDE + ch * 16] = stg[t][h];
        }
    __syncthreads();

    const char* A1l = &lds[(sg ? 1 : 0) * 64 * TSTRIDE];
    const char* A2l = &lds[2 * 64 * TSTRIDE];
    float* op = out + (sg ? 128 : 0);
    #pragma unroll 2
    for (int rt = 0; rt < 4; ++rt) {
        const int lrow = rt * 16 + m;
        const char* a1p = A1l + lrow * TSTRIDE + q * 16;
        const char* a2p = A2l + lrow * TSTRIDE + q * 16;
        float4v c0a = {0.f,0.f,0.f,0.f}, c0b = {0.f,0.f,0.f,0.f};
        float4v c1a = {0.f,0.f,0.f,0.f}, c1b = {0.f,0.f,0.f,0.f};
        #pragma unroll
        for (int c = 0; c < 4; ++c) {
            short8 a = *(const short8*)(a1p + c * 64);
            short8 b = *(const short8*)(a2p + c * 64);
            c0a = __builtin_amdgcn_mfma_f32_16x16x32_bf16(a, B1[0][c], c0a, 0, 0, 0);
            c1a = __builtin_amdgcn_mfma_f32_16x16x32_bf16(a, B1[1][c], c1a, 0, 0, 0);
            c0b = __builtin_amdgcn_mfma_f32_16x16x32_bf16(b, B2[0][c], c0b, 0, 0, 0);
            c1b = __builtin_amdgcn_mfma_f32_16x16x32_bf16(b, B2[1][c], c1b, 0, 0, 0);
        }
        #pragma unroll
        for (int r = 0; r < 4; ++r) {
            int ro = rb + rt * 16 + q * 4 + r;
            if (ro < N) {
                float v0 = c0a[r] + c0b[r] + b0;
                float v1 = c1a[r] + c1b[r] + b1;
                if (!sg) { v0 = fmaxf(v0, 0.f); v1 = fmaxf(v1, 0.f); }
                else     { v0 = act_leaky_elu(v0); v1 = act_leaky_elu(v1); }
                op[(size_t)ro * 256 + cg + m]      = v0;
                op[(size_t)ro * 256 + cg + 16 + m] = v1;
            }
        }
    }
}

extern "C" void kernel_launch(void* const* d_in, const int* in_sizes, int n_in,
                              void* d_out, int out_size, void* d_ws, size_t ws_size,
                              hipStream_t stream) {
    const float* x    = (const float*)d_in[0];
    const int*   ei   = (const int*)d_in[1];
    const float* ew   = (const float*)d_in[2];
    const float* Wpre = (const float*)d_in[3];
    const float* bpre = (const float*)d_in[4];
    const float* Wai  = (const float*)d_in[5];
    const float* War  = (const float*)d_in[6];
    const float* ab   = (const float*)d_in[7];
    const float* Wsl  = (const float*)d_in[8];
    const float* bsl  = (const float*)d_in[9];
    const float* Wsr  = (const float*)d_in[10];

    const int N = in_sizes[0] / 128;
    const int E = in_sizes[2];
    const size_t NF = (size_t)N * 128;
    const int NBKT = (N + 127) >> 7;
    const bool packed = (N <= 130944);   // NBKT+1 <= 1024 and src fits 17 bits

    char* p = (char*)d_ws;
    auto take = [&p](size_t bytes) {
        char* r = p;
        p += (bytes + 255) & ~(size_t)255;
        return r;
    };
    unsigned short* hb  = (unsigned short*)take(NF * 2);
    unsigned short* agb = (unsigned short*)take(NF * 2);
    unsigned short* mnb = (unsigned short*)take(NF * 2);
    unsigned* recs = (unsigned*)take(packed ? (size_t)E * 4 : (size_t)E * 8);
    int*   rowp = (int*)take((size_t)(N + 1) * 4);
    float* dis  = (float*)take((size_t)N * 4);
    int*   cti  = (int*)take((size_t)(N + 1) * 4);   // fallback count
    int*   blks = (int*)take(128 * 4);
    int*   gcnt = (int*)take(1025 * 4);
    uint4* pw   = (uint4*)take((size_t)5 * 2048 * 16);

    // overlays (packed path): binned on agb; aux+bbase on mnb.
    size_t binB = (size_t)E * 8;
    uint2* binned = (NF * 2 >= binB) ? (uint2*)agb : (uint2*)take(binB);
    size_t auxB = ((size_t)E * 4 + 255) & ~(size_t)255;
    size_t bbB  = (size_t)NB_BIN * 1024 * 4;
    unsigned* aux; int* bbase;
    if (NF * 2 >= auxB + bbB) {
        aux = (unsigned*)mnb;
        bbase = (int*)((char*)mnb + auxB);
    } else {
        aux = (unsigned*)take((size_t)E * 4);
        bbase = (int*)take(bbB);
    }

    const int gd = (N + 127) / 128;
    const int gf = (N + 63) / 64;
    const int ge = (E + 255) / 256;
    const int gv = (N + 255) / 256;
    const int ns = N + 1;
    const int nb = (ns + 1023) / 1024;

    k_prep<<<5, 256, 0, stream>>>(Wpre, Wai, War, Wsl, Wsr, pw);

    if (packed) {
        hipMemsetAsync(gcnt, 0, (size_t)(NBKT + 1) * 4, stream);
        k_pre_bin1<<<gd + NB_BIN, 256, 0, stream>>>(x, pw, bpre, hb, N, gd,
                                                    ei, gcnt, aux, bbase,
                                                    E, NBKT);
        k_bin2<<<NB_BIN, 256, 0, stream>>>(ei, ew, aux, gcnt, bbase,
                                           binned, E, NBKT);
        k_bktcsr<<<NBKT, 256, 0, stream>>>(binned, gcnt, recs, rowp, dis,
                                           N, E, NBKT);
        k_pull<true><<<(N + 3) / 4, 256, 0, stream>>>(rowp, blks, recs, dis,
            (const uint4*)hb, (uint4*)agb, (uint4*)mnb, N);
    } else {
        hipMemsetAsync(cti, 0, (size_t)(N + 1) * 4, stream);
        k_pre_cntD<<<gd + 2048, 256, 0, stream>>>(x, pw, bpre, hb, N, gd,
                                                  ei, cti, (int*)aux, E);
        k_scan1<<<nb, 256, 0, stream>>>(cti, rowp, blks, ns);
        k_scan2<<<1, 128, 0, stream>>>(blks, nb);
        k_scatterW<<<ge, 256, 0, stream>>>(ei, ew, rowp, blks, (int*)aux,
                                           (int2*)recs, E);
        k_degsumW<<<gv, 256, 0, stream>>>(rowp, blks, (const int2*)recs,
                                          dis, N);
        k_pull<false><<<(N + 3) / 4, 256, 0, stream>>>(rowp, blks, recs, dis,
            (const uint4*)hb, (uint4*)agb, (uint4*)mnb, N);
    }

    k_final2<<<gf, 512, 0, stream>>>(agb, mnb, hb, pw, ab, bsl,
                                     (float*)d_out, N);
}